// Round 1
// baseline (249.140 us; speedup 1.0000x reference)
//
#include <hip/hip_runtime.h>
#include <stdint.h>

typedef unsigned short ushort_t;
typedef __bf16 bf16x8 __attribute__((ext_vector_type(8)));
typedef float f32x4 __attribute__((ext_vector_type(4)));

#define M_TOK 8192
#define K1 1024
#define N1 4096
#define K2 4160   /* 4096 (h) + 16 (probs/b2) + 48 zero-pad -> 65 K-steps of 64 */
#define N2 1024

__device__ __forceinline__ ushort_t f2bf(float f) {
  union { float f; unsigned u; } v; v.f = f;
  unsigned u = v.u;
  u += 0x7FFFu + ((u >> 16) & 1u);   // RNE; inputs finite
  return (ushort_t)(u >> 16);
}

__device__ __forceinline__ void gload16(const void* g, void* l) {
  __builtin_amdgcn_global_load_lds((__attribute__((address_space(1))) void*)g,
                                   (__attribute__((address_space(3))) void*)l,
                                   16, 0, 0);
}

// ---------------- probs + x -> bf16 ----------------
// 1 wave per token: 15 sigmoid gates, tree product, write probs (f32),
// write bf16 x row, and fill hp's extra K-columns (probs bf16 + zeros).
__global__ __launch_bounds__(256) void k_probs(
    const float* __restrict__ x, const float* __restrict__ node_w,
    const float* __restrict__ node_b, ushort_t* __restrict__ xb,
    float* __restrict__ probs, ushort_t* __restrict__ hp) {
  const int wid = threadIdx.x >> 6, lane = threadIdx.x & 63;
  const int t = blockIdx.x * 4 + wid;
  const float* xr = x + (size_t)t * K1;
  float xv[16];
#pragma unroll
  for (int j = 0; j < 4; ++j) {
    float4 v = *(const float4*)(xr + j * 256 + lane * 4);
    xv[4*j+0] = v.x; xv[4*j+1] = v.y; xv[4*j+2] = v.z; xv[4*j+3] = v.w;
  }
  ushort_t* xbr = xb + (size_t)t * K1;
#pragma unroll
  for (int j = 0; j < 4; ++j) {
    ushort4 o;
    o.x = f2bf(xv[4*j+0]); o.y = f2bf(xv[4*j+1]);
    o.z = f2bf(xv[4*j+2]); o.w = f2bf(xv[4*j+3]);
    *(ushort4*)(xbr + j * 256 + lane * 4) = o;
  }
  float c[15];
#pragma unroll
  for (int n = 0; n < 15; ++n) {
    float s = 0.f;
    const float* wr = node_w + n * K1;
#pragma unroll
    for (int j = 0; j < 4; ++j) {
      float4 w = *(const float4*)(wr + j * 256 + lane * 4);
      s += xv[4*j+0]*w.x + xv[4*j+1]*w.y + xv[4*j+2]*w.z + xv[4*j+3]*w.w;
    }
#pragma unroll
    for (int off = 32; off > 0; off >>= 1) s += __shfl_xor(s, off);
    float z = s + node_b[n];
    c[n] = 1.f / (1.f + __expf(-z));
  }
  if (lane < 16) {
    float p = 1.f;
#pragma unroll
    for (int m = 0; m < 4; ++m) {
      int jm = lane >> (4 - m);
      int node = (1 << m) - 1 + jm;
      int bit = (lane >> (3 - m)) & 1;
      p *= bit ? (1.f - c[node]) : c[node];   // bit 0 => c, bit 1 => 1-c
    }
    probs[t * 16 + lane] = p;
    hp[(size_t)t * K2 + 4096 + lane] = f2bf(p);
  }
  if (lane < 48) hp[(size_t)t * K2 + 4112 + lane] = 0;  // zero pad cols
}

// ---------------- w1 (16,1024,256) -> w1t (4096 x 1024) bf16 ----------------
// w1t[l*256+h][k] = w1[l][k][h]
__global__ __launch_bounds__(256) void k_w1t(const float* __restrict__ w1,
                                             ushort_t* __restrict__ w1t) {
  __shared__ ushort_t tile[64][68];
  const int b = blockIdx.x;             // 16 leaves * 16 ktiles * 4 htiles
  const int l = b >> 6, rem = b & 63;
  const int kt = rem >> 2, ht = rem & 3;
  const float* in = w1 + (size_t)l * K1 * 256;
  const int tr = threadIdx.x >> 4;
  const int tc = (threadIdx.x & 15) * 4;
#pragma unroll
  for (int rr = 0; rr < 4; ++rr) {
    int r = tr + rr * 16;               // k_local
    float4 v = *(const float4*)(in + (size_t)(kt * 64 + r) * 256 + ht * 64 + tc);
    tile[r][tc+0] = f2bf(v.x); tile[r][tc+1] = f2bf(v.y);
    tile[r][tc+2] = f2bf(v.z); tile[r][tc+3] = f2bf(v.w);
  }
  __syncthreads();
#pragma unroll
  for (int rr = 0; rr < 4; ++rr) {
    int oh = tr + rr * 16;              // h_local
    ushort4 o;
    o.x = tile[tc+0][oh]; o.y = tile[tc+1][oh];
    o.z = tile[tc+2][oh]; o.w = tile[tc+3][oh];
    *(ushort4*)(w1t + (size_t)(l * 256 + ht * 64 + oh) * K1 + kt * 64 + tc) = o;
  }
}

// ---------------- w2 (16,256,1024) -> w2t (1024 x 4160) bf16 ----------------
// w2t[d][l*256+h] = w2[l][h][d]
__global__ __launch_bounds__(256) void k_w2t(const float* __restrict__ w2,
                                             ushort_t* __restrict__ w2t) {
  __shared__ ushort_t tile[64][68];
  const int b = blockIdx.x;             // 16 leaves * 4 htiles * 16 dtiles
  const int l = b >> 6, rem = b & 63;
  const int ht = rem >> 4, dt = rem & 15;
  const float* in = w2 + (size_t)l * 256 * N2;
  const int tr = threadIdx.x >> 4;
  const int tc = (threadIdx.x & 15) * 4;
#pragma unroll
  for (int rr = 0; rr < 4; ++rr) {
    int r = tr + rr * 16;               // h_local
    float4 v = *(const float4*)(in + (size_t)(ht * 64 + r) * N2 + dt * 64 + tc);
    tile[r][tc+0] = f2bf(v.x); tile[r][tc+1] = f2bf(v.y);
    tile[r][tc+2] = f2bf(v.z); tile[r][tc+3] = f2bf(v.w);
  }
  __syncthreads();
#pragma unroll
  for (int rr = 0; rr < 4; ++rr) {
    int od = tr + rr * 16;              // d_local
    ushort4 o;
    o.x = tile[tc+0][od]; o.y = tile[tc+1][od];
    o.z = tile[tc+2][od]; o.w = tile[tc+3][od];
    *(ushort4*)(w2t + (size_t)(dt * 64 + od) * K2 + l * 256 + ht * 64 + tc) = o;
  }
}

// ---------------- b2 rows + zero pad into w2t cols 4096..4159 ----------------
__global__ __launch_bounds__(256) void k_b2pad(const float* __restrict__ b2,
                                               ushort_t* __restrict__ w2t) {
  int tid = blockIdx.x * 256 + threadIdx.x;   // 1024 * 64
  int d = tid >> 6, cc = tid & 63;
  float v = (cc < 16) ? b2[cc * N2 + d] : 0.f;
  w2t[(size_t)d * K2 + 4096 + cc] = f2bf(v);
}

// ---------------- MFMA GEMM: C[m][n] = sum_k A[m][k] * Bt[n][k] ----------------
// 128x128 tile, BK=64, 4 waves (each 64x64 = 4x4 frags of 16x16x32).
// MODE 0: epilogue = +b1, relu, *probs -> bf16 hp (row stride K2)
// MODE 1: epilogue = f32 store to out (b2 term included via extended K)
template <int KTOT, int LDA, int LDB, int MODE>
__global__ __launch_bounds__(256) void k_gemm(
    const ushort_t* __restrict__ A, const ushort_t* __restrict__ Bt,
    const float* __restrict__ probs, const float* __restrict__ b1,
    ushort_t* __restrict__ hp, float* __restrict__ out, int ntn) {
  __shared__ __align__(16) ushort_t Asm[128 * 64];
  __shared__ __align__(16) ushort_t Bsm[128 * 64];
  const int tid = threadIdx.x;
  const int bm = blockIdx.x / ntn, bn = blockIdx.x % ntn;
  const int wid = tid >> 6, lane = tid & 63;
  const int wm = (wid >> 1) * 64, wn = (wid & 1) * 64;
  const int lr = lane & 15, lk = (lane >> 4) * 8;
  const ushort_t* Ag = A + (size_t)bm * 128 * LDA;
  const ushort_t* Bg = Bt + (size_t)bn * 128 * LDB;

  f32x4 acc[4][4];
#pragma unroll
  for (int i = 0; i < 4; ++i)
#pragma unroll
    for (int j = 0; j < 4; ++j)
      acc[i][j] = (f32x4){0.f, 0.f, 0.f, 0.f};

#pragma unroll 1
  for (int kt = 0; kt < KTOT / 64; ++kt) {
    const ushort_t* Ak = Ag + kt * 64;
    const ushort_t* Bk = Bg + kt * 64;
#pragma unroll
    for (int r = 0; r < 4; ++r) {
      int row = r * 32 + (tid >> 3);
      int ke = (tid & 7) * 8;
      gload16(Ak + (size_t)row * LDA + ke, Asm + row * 64 + ke);
      gload16(Bk + (size_t)row * LDB + ke, Bsm + row * 64 + ke);
    }
    __syncthreads();   // drains vmcnt for global_load_lds
#pragma unroll
    for (int kk = 0; kk < 2; ++kk) {
      bf16x8 af[4], bfr[4];
#pragma unroll
      for (int i = 0; i < 4; ++i)
        af[i] = *(const bf16x8*)(Asm + (wm + i * 16 + lr) * 64 + kk * 32 + lk);
#pragma unroll
      for (int j = 0; j < 4; ++j)
        bfr[j] = *(const bf16x8*)(Bsm + (wn + j * 16 + lr) * 64 + kk * 32 + lk);
#pragma unroll
      for (int i = 0; i < 4; ++i)
#pragma unroll
        for (int j = 0; j < 4; ++j)
          acc[i][j] = __builtin_amdgcn_mfma_f32_16x16x32_bf16(af[i], bfr[j], acc[i][j], 0, 0, 0);
    }
    __syncthreads();
  }

  // C/D layout (m89-verified): col = lane&15, row = (lane>>4)*4 + reg
  const int rowb = bm * 128 + wm + ((lane >> 4) << 2);
  const int colb = bn * 128 + wn + lr;
  if (MODE == 0) {
    const int lleaf = bn >> 1;   // 128-wide tile lies within one 256-wide leaf
    float pm[4][4];
#pragma unroll
    for (int i = 0; i < 4; ++i)
#pragma unroll
      for (int q = 0; q < 4; ++q)
        pm[i][q] = probs[(size_t)(rowb + i * 16 + q) * 16 + lleaf];
#pragma unroll
    for (int j = 0; j < 4; ++j) {
      int n = colb + j * 16;
      float bias = b1[n];
#pragma unroll
      for (int i = 0; i < 4; ++i)
#pragma unroll
        for (int q = 0; q < 4; ++q) {
          float v = acc[i][j][q] + bias;
          v = v > 0.f ? v : 0.f;
          v *= pm[i][q];
          hp[(size_t)(rowb + i * 16 + q) * K2 + n] = f2bf(v);
        }
    }
  } else {
#pragma unroll
    for (int j = 0; j < 4; ++j) {
      int n = colb + j * 16;
#pragma unroll
      for (int i = 0; i < 4; ++i)
#pragma unroll
        for (int q = 0; q < 4; ++q)
          out[(size_t)(rowb + i * 16 + q) * N2 + n] = acc[i][j][q];
    }
  }
}

extern "C" void kernel_launch(void* const* d_in, const int* in_sizes, int n_in,
                              void* d_out, int out_size, void* d_ws, size_t ws_size,
                              hipStream_t stream) {
  const float* x      = (const float*)d_in[0];
  const float* node_w = (const float*)d_in[1];
  const float* node_b = (const float*)d_in[2];
  const float* w1     = (const float*)d_in[3];
  const float* b1     = (const float*)d_in[4];
  const float* w2     = (const float*)d_in[5];
  const float* b2     = (const float*)d_in[6];
  float* out = (float*)d_out;

  char* ws = (char*)d_ws;
  // ws layout (bytes): xb 16MB | w1t 8MB | w2t 8.5MB | hp 65MB | probs 0.5MB
  ushort_t* xb    = (ushort_t*)(ws);
  ushort_t* w1t   = (ushort_t*)(ws + 16777216);
  ushort_t* w2t   = (ushort_t*)(ws + 25165824);
  ushort_t* hp    = (ushort_t*)(ws + 33685504);
  float*    probs = (float*)   (ws + 101842944);
  // total = 102,367,232 bytes

  k_probs<<<M_TOK / 4, 256, 0, stream>>>(x, node_w, node_b, xb, probs, hp);
  k_w1t<<<1024, 256, 0, stream>>>(w1, w1t);
  k_w2t<<<1024, 256, 0, stream>>>(w2, w2t);
  k_b2pad<<<256, 256, 0, stream>>>(b2, w2t);
  k_gemm<K1, K1, K1, 0><<<(M_TOK / 128) * (N1 / 128), 256, 0, stream>>>(
      xb, w1t, probs, b1, hp, nullptr, N1 / 128);
  k_gemm<K2, K2, K2, 1><<<(M_TOK / 128) * (N2 / 128), 256, 0, stream>>>(
      hp, w2t, nullptr, nullptr, nullptr, out, N2 / 128);
}

// Round 2
// 190.118 us; speedup vs baseline: 1.3104x; 1.3104x over previous
//
#include <hip/hip_runtime.h>
#include <stdint.h>

typedef unsigned short ushort_t;
typedef __bf16 bf16x8 __attribute__((ext_vector_type(8)));
typedef float f32x4 __attribute__((ext_vector_type(4)));

#define M_TOK 8192
#define K1 1024
#define N1 4096
#define K2 4160   /* 4096 (h) + 16 (probs/b2) + 48 zero-pad -> 65 K-steps of 64 */
#define N2 1024

__device__ __forceinline__ ushort_t f2bf(float f) {
  union { float f; unsigned u; } v; v.f = f;
  unsigned u = v.u;
  u += 0x7FFFu + ((u >> 16) & 1u);   // RNE; inputs finite
  return (ushort_t)(u >> 16);
}

__device__ __forceinline__ void gload16(const void* g, void* l) {
  __builtin_amdgcn_global_load_lds((__attribute__((address_space(1))) void*)g,
                                   (__attribute__((address_space(3))) void*)l,
                                   16, 0, 0);
}

// ---------------- probs + x -> bf16 ----------------
__global__ __launch_bounds__(256) void k_probs(
    const float* __restrict__ x, const float* __restrict__ node_w,
    const float* __restrict__ node_b, ushort_t* __restrict__ xb,
    float* __restrict__ probs, ushort_t* __restrict__ hp) {
  const int wid = threadIdx.x >> 6, lane = threadIdx.x & 63;
  const int t = blockIdx.x * 4 + wid;
  const float* xr = x + (size_t)t * K1;
  float xv[16];
#pragma unroll
  for (int j = 0; j < 4; ++j) {
    float4 v = *(const float4*)(xr + j * 256 + lane * 4);
    xv[4*j+0] = v.x; xv[4*j+1] = v.y; xv[4*j+2] = v.z; xv[4*j+3] = v.w;
  }
  ushort_t* xbr = xb + (size_t)t * K1;
#pragma unroll
  for (int j = 0; j < 4; ++j) {
    ushort4 o;
    o.x = f2bf(xv[4*j+0]); o.y = f2bf(xv[4*j+1]);
    o.z = f2bf(xv[4*j+2]); o.w = f2bf(xv[4*j+3]);
    *(ushort4*)(xbr + j * 256 + lane * 4) = o;
  }
  float c[15];
#pragma unroll
  for (int n = 0; n < 15; ++n) {
    float s = 0.f;
    const float* wr = node_w + n * K1;
#pragma unroll
    for (int j = 0; j < 4; ++j) {
      float4 w = *(const float4*)(wr + j * 256 + lane * 4);
      s += xv[4*j+0]*w.x + xv[4*j+1]*w.y + xv[4*j+2]*w.z + xv[4*j+3]*w.w;
    }
#pragma unroll
    for (int off = 32; off > 0; off >>= 1) s += __shfl_xor(s, off);
    float z = s + node_b[n];
    c[n] = 1.f / (1.f + __expf(-z));
  }
  if (lane < 16) {
    float p = 1.f;
#pragma unroll
    for (int m = 0; m < 4; ++m) {
      int jm = lane >> (4 - m);
      int node = (1 << m) - 1 + jm;
      int bit = (lane >> (3 - m)) & 1;
      p *= bit ? (1.f - c[node]) : c[node];
    }
    probs[t * 16 + lane] = p;
    hp[(size_t)t * K2 + 4096 + lane] = f2bf(p);
  }
  if (lane < 48) hp[(size_t)t * K2 + 4112 + lane] = 0;
}

// ---------------- w1 (16,1024,256) -> w1t (4096 x 1024) bf16 ----------------
__global__ __launch_bounds__(256) void k_w1t(const float* __restrict__ w1,
                                             ushort_t* __restrict__ w1t) {
  __shared__ ushort_t tile[64][68];
  const int b = blockIdx.x;
  const int l = b >> 6, rem = b & 63;
  const int kt = rem >> 2, ht = rem & 3;
  const float* in = w1 + (size_t)l * K1 * 256;
  const int tr = threadIdx.x >> 4;
  const int tc = (threadIdx.x & 15) * 4;
#pragma unroll
  for (int rr = 0; rr < 4; ++rr) {
    int r = tr + rr * 16;
    float4 v = *(const float4*)(in + (size_t)(kt * 64 + r) * 256 + ht * 64 + tc);
    tile[r][tc+0] = f2bf(v.x); tile[r][tc+1] = f2bf(v.y);
    tile[r][tc+2] = f2bf(v.z); tile[r][tc+3] = f2bf(v.w);
  }
  __syncthreads();
#pragma unroll
  for (int rr = 0; rr < 4; ++rr) {
    int oh = tr + rr * 16;
    ushort4 o;
    o.x = tile[tc+0][oh]; o.y = tile[tc+1][oh];
    o.z = tile[tc+2][oh]; o.w = tile[tc+3][oh];
    *(ushort4*)(w1t + (size_t)(l * 256 + ht * 64 + oh) * K1 + kt * 64 + tc) = o;
  }
}

// ---------------- w2 (16,256,1024) -> w2t (1024 x 4160) bf16 ----------------
__global__ __launch_bounds__(256) void k_w2t(const float* __restrict__ w2,
                                             ushort_t* __restrict__ w2t) {
  __shared__ ushort_t tile[64][68];
  const int b = blockIdx.x;
  const int l = b >> 6, rem = b & 63;
  const int ht = rem >> 4, dt = rem & 15;
  const float* in = w2 + (size_t)l * 256 * N2;
  const int tr = threadIdx.x >> 4;
  const int tc = (threadIdx.x & 15) * 4;
#pragma unroll
  for (int rr = 0; rr < 4; ++rr) {
    int r = tr + rr * 16;
    float4 v = *(const float4*)(in + (size_t)(ht * 64 + r) * N2 + dt * 64 + tc);
    tile[r][tc+0] = f2bf(v.x); tile[r][tc+1] = f2bf(v.y);
    tile[r][tc+2] = f2bf(v.z); tile[r][tc+3] = f2bf(v.w);
  }
  __syncthreads();
#pragma unroll
  for (int rr = 0; rr < 4; ++rr) {
    int od = tr + rr * 16;
    ushort4 o;
    o.x = tile[tc+0][od]; o.y = tile[tc+1][od];
    o.z = tile[tc+2][od]; o.w = tile[tc+3][od];
    *(ushort4*)(w2t + (size_t)(dt * 64 + od) * K2 + l * 256 + ht * 64 + tc) = o;
  }
}

__global__ __launch_bounds__(256) void k_b2pad(const float* __restrict__ b2,
                                               ushort_t* __restrict__ w2t) {
  int tid = blockIdx.x * 256 + threadIdx.x;
  int d = tid >> 6, cc = tid & 63;
  float v = (cc < 16) ? b2[cc * N2 + d] : 0.f;
  w2t[(size_t)d * K2 + 4096 + cc] = f2bf(v);
}

// ---------------- 256xBN deep-pipelined MFMA GEMM ----------------
// BM=256, BK=64, 8 waves (512 thr). BN=256: 2Mx4N waves, 4 phases/K-tile,
// vmcnt(6). BN=128: 4Mx2N waves, 2 phases/K-tile, vmcnt(4). A-halves are
// phase-local (q selects half); stage schedule: A1(t+1)@first phase,
// A0(t+2)+B0B1(t+2)@last phases. LDS XOR-swizzle (st_16x32) applied as
// linear gload_lds dest + inverse-swizzled GLOBAL source + swizzled read.
template <int NT, int LDA, int LDB, int BN, int MODE>
__global__ __launch_bounds__(512, 2) void k_gemm8(
    const ushort_t* __restrict__ A, const ushort_t* __restrict__ Bt,
    const float* __restrict__ probs, const float* __restrict__ b1,
    ushort_t* __restrict__ hp, float* __restrict__ out, int ntn) {
  constexpr int BHR = BN / 2;                 // B half rows
  constexpr int WN = (BN == 256) ? 4 : 2;
  constexpr int WM = 8 / WN;
  constexpr int FH = 128 / (WM * 16);         // m-frags per half per wave
  constexpr int PHN = (BN == 256) ? 4 : 2;    // phases per K-tile
  constexpr int ABYTES = 128 * 128;
  constexpr int BBYTES = BHR * 128;

  extern __shared__ char lds[];
  // A slots: [buf][half] 16KB each; B slots after 64KB.
  const int tid = threadIdx.x;
  int bid = blockIdx.x;
  const int nwg = gridDim.x;                  // divisible by 8
  bid = (bid & 7) * (nwg >> 3) + (bid >> 3);  // XCD swizzle (bijective)
  const int bm = bid / ntn, bn = bid % ntn;

  const int wid = tid >> 6, lane = tid & 63;
  const int widM = wid / WN, widN = wid % WN;
  const int wmBase = widM * (FH * 16);
  const int wn = widN * 64;
  const int lr = lane & 15, g = lane >> 4;

  const ushort_t* Ag = A + (size_t)bm * 256 * LDA;
  const ushort_t* Bg = Bt + (size_t)bn * BN * LDB;

  // staging: thread covers (row srow [+64*rnd], 16B-slot tid&7) of a half,
  // LDS dest linear; source col pre-XOR'd so swizzled reads see logical data.
  const int srow = tid >> 3;
  const int scol = ((tid & 7) << 4) ^ ((srow & 7) << 4);

  auto stageA = [&](int buf, int half, int kt) {
    const ushort_t* src = Ag + (size_t)(half * 128) * LDA + kt * 64;
    char* dst = lds + (buf * 2 + half) * ABYTES + tid * 16;
#pragma unroll
    for (int r = 0; r < 2; ++r)
      gload16((const char*)(src + (size_t)(srow + r * 64) * LDA) + scol,
              dst + r * 8192);
  };
  auto stageB = [&](int buf, int half, int kt) {
    const ushort_t* src = Bg + (size_t)(half * BHR) * LDB + kt * 64;
    char* dst = lds + 4 * ABYTES + (buf * 2 + half) * BBYTES + tid * 16;
#pragma unroll
    for (int r = 0; r < BHR / 64; ++r)
      gload16((const char*)(src + (size_t)(srow + r * 64) * LDB) + scol,
              dst + r * 8192);
  };
  auto rdA = [&](int buf, int half, int i, int kk) -> bf16x8 {
    int r = wmBase + i * 16 + lr;
    int off = r * 128 + (((kk * 4 + g) ^ (lr & 7)) << 4);
    return *(const bf16x8*)(lds + (buf * 2 + half) * ABYTES + off);
  };
  auto rdB = [&](int buf, int j, int kk) -> bf16x8 {
    int nr = wn + j * 16;
    int half = (nr >= BHR) ? 1 : 0;
    int r = (nr & (BHR - 1)) + lr;
    int off = r * 128 + (((kk * 4 + g) ^ (lr & 7)) << 4);
    return *(const bf16x8*)(lds + 4 * ABYTES + (buf * 2 + half) * BBYTES + off);
  };

  f32x4 acc[2 * FH][4];
#pragma unroll
  for (int i = 0; i < 2 * FH; ++i)
#pragma unroll
    for (int j = 0; j < 4; ++j) acc[i][j] = (f32x4){0.f, 0.f, 0.f, 0.f};

  // prologue: tile0 fully + {A0,B0,B1}(1); A1(1) issued in group 0 phase 0.
  stageA(0, 0, 0); stageB(0, 0, 0); stageB(0, 1, 0); stageA(0, 1, 0);
  stageA(1, 0, 1); stageB(1, 0, 1); stageB(1, 1, 1);
  if constexpr (BN == 256) asm volatile("s_waitcnt vmcnt(6)" ::: "memory");
  else                     asm volatile("s_waitcnt vmcnt(4)" ::: "memory");
  __builtin_amdgcn_sched_barrier(0);
  __builtin_amdgcn_s_barrier();

#pragma unroll 1
  for (int kt = 0; kt < NT; ++kt) {
    const int cur = kt & 1;
    bf16x8 bfr[2][4];
#pragma unroll
    for (int ph = 0; ph < PHN; ++ph) {
      constexpr int KKN = (PHN == 4) ? 1 : 2;
      const int q = (PHN == 4) ? (ph >> 1) : ph;
      bf16x8 af[FH][KKN];
#pragma unroll
      for (int kx = 0; kx < KKN; ++kx) {
        const int kk = (PHN == 4) ? (ph & 1) : kx;
#pragma unroll
        for (int i = 0; i < FH; ++i) af[i][kx] = rdA(cur, q, i, kk);
        if (q == 0) {
#pragma unroll
          for (int j = 0; j < 4; ++j) bfr[kk][j] = rdB(cur, j, kk);
        }
      }
      // staging issues (after reads, before barrier)
      if (ph == 0 && kt + 1 < NT) stageA(cur ^ 1, 1, kt + 1);
      if (PHN == 4 && ph == 2 && kt + 2 < NT) stageA(cur, 0, kt + 2);
      if (ph == PHN - 1 && kt + 2 < NT) {
        if (PHN == 2) stageA(cur, 0, kt + 2);
        stageB(cur, 0, kt + 2); stageB(cur, 1, kt + 2);
      }
      __builtin_amdgcn_sched_barrier(0x7);
      __builtin_amdgcn_s_barrier();
      __builtin_amdgcn_sched_barrier(0x7);
      __builtin_amdgcn_s_setprio(1);
#pragma unroll
      for (int kx = 0; kx < KKN; ++kx) {
        const int kk = (PHN == 4) ? (ph & 1) : kx;
#pragma unroll
        for (int i = 0; i < FH; ++i)
#pragma unroll
          for (int j = 0; j < 4; ++j)
            acc[q * FH + i][j] = __builtin_amdgcn_mfma_f32_16x16x32_bf16(
                af[i][kx], bfr[kk][j], acc[q * FH + i][j], 0, 0, 0);
      }
      __builtin_amdgcn_s_setprio(0);
      if (ph == PHN - 1) {
        if (kt + 2 < NT) {
          if constexpr (BN == 256) asm volatile("s_waitcnt vmcnt(6)" ::: "memory");
          else                     asm volatile("s_waitcnt vmcnt(4)" ::: "memory");
          __builtin_amdgcn_sched_barrier(0);
        } else if (kt + 1 < NT) {
          asm volatile("s_waitcnt vmcnt(0)" ::: "memory");
          __builtin_amdgcn_sched_barrier(0);
        }
      }
      __builtin_amdgcn_sched_barrier(0x7);
      __builtin_amdgcn_s_barrier();
      __builtin_amdgcn_sched_barrier(0x7);
    }
  }

  // epilogue: C/D layout col=lane&15, row=(lane>>4)*4+reg
  const int rowb = bm * 256 + wmBase + g * 4;
  const int colb = bn * BN + wn + lr;
  if (MODE == 0) {
    const int leaf = bn;   // BN=256 tile == one leaf
#pragma unroll
    for (int q = 0; q < 2; ++q)
#pragma unroll
      for (int i = 0; i < FH; ++i) {
        int rbase = rowb + q * 128 + i * 16;
        float pm[4];
#pragma unroll
        for (int rg = 0; rg < 4; ++rg)
          pm[rg] = probs[(size_t)(rbase + rg) * 16 + leaf];
#pragma unroll
        for (int j = 0; j < 4; ++j) {
          float bias = b1[colb + j * 16];
#pragma unroll
          for (int rg = 0; rg < 4; ++rg) {
            float v = acc[q * FH + i][j][rg] + bias;
            v = v > 0.f ? v : 0.f;
            v *= pm[rg];
            hp[(size_t)(rbase + rg) * K2 + colb + j * 16] = f2bf(v);
          }
        }
      }
  } else {
#pragma unroll
    for (int q = 0; q < 2; ++q)
#pragma unroll
      for (int i = 0; i < FH; ++i) {
        int rbase = rowb + q * 128 + i * 16;
#pragma unroll
        for (int j = 0; j < 4; ++j)
#pragma unroll
          for (int rg = 0; rg < 4; ++rg)
            out[(size_t)(rbase + rg) * N2 + colb + j * 16] = acc[q * FH + i][j][rg];
      }
  }
}

extern "C" void kernel_launch(void* const* d_in, const int* in_sizes, int n_in,
                              void* d_out, int out_size, void* d_ws, size_t ws_size,
                              hipStream_t stream) {
  const float* x      = (const float*)d_in[0];
  const float* node_w = (const float*)d_in[1];
  const float* node_b = (const float*)d_in[2];
  const float* w1     = (const float*)d_in[3];
  const float* b1     = (const float*)d_in[4];
  const float* w2     = (const float*)d_in[5];
  const float* b2     = (const float*)d_in[6];
  float* out = (float*)d_out;

  char* ws = (char*)d_ws;
  ushort_t* xb    = (ushort_t*)(ws);
  ushort_t* w1t   = (ushort_t*)(ws + 16777216);
  ushort_t* w2t   = (ushort_t*)(ws + 25165824);
  ushort_t* hp    = (ushort_t*)(ws + 33685504);
  float*    probs = (float*)   (ws + 101842944);

  k_probs<<<M_TOK / 4, 256, 0, stream>>>(x, node_w, node_b, xb, probs, hp);
  k_w1t<<<1024, 256, 0, stream>>>(w1, w1t);
  k_w2t<<<1024, 256, 0, stream>>>(w2, w2t);
  k_b2pad<<<256, 256, 0, stream>>>(b2, w2t);
  // GEMM1: 8192x4096, K=1024: 32x16=512 blocks, BN=256, LDS 128 KiB
  k_gemm8<16, K1, K1, 256, 0><<<512, 512, 131072, stream>>>(
      xb, w1t, probs, b1, hp, nullptr, N1 / 256);
  // GEMM2: 8192x1024, K=4160: 32x8=256 blocks, BN=128, LDS 96 KiB
  k_gemm8<65, K2, K2, 128, 1><<<256, 512, 98304, stream>>>(
      hp, w2t, nullptr, nullptr, nullptr, out, N2 / 128);
}

// Round 3
// 190.045 us; speedup vs baseline: 1.3109x; 1.0004x over previous
//
#include <hip/hip_runtime.h>
#include <stdint.h>

typedef unsigned short ushort_t;
typedef __bf16 bf16x8 __attribute__((ext_vector_type(8)));
typedef float f32x4 __attribute__((ext_vector_type(4)));

#define M_TOK 8192
#define K1 1024
#define N1 4096
#define K2 4160   /* 4096 (h) + 16 (probs/b2) + 48 zero-pad -> 65 K-steps of 64 */
#define N2 1024

__device__ __forceinline__ ushort_t f2bf(float f) {
  union { float f; unsigned u; } v; v.f = f;
  unsigned u = v.u;
  u += 0x7FFFu + ((u >> 16) & 1u);   // RNE; inputs finite
  return (ushort_t)(u >> 16);
}

__device__ __forceinline__ void gload16(const void* g, void* l) {
  __builtin_amdgcn_global_load_lds((__attribute__((address_space(1))) void*)g,
                                   (__attribute__((address_space(3))) void*)l,
                                   16, 0, 0);
}

// ---------------- probs + x -> bf16 ----------------
__global__ __launch_bounds__(256) void k_probs(
    const float* __restrict__ x, const float* __restrict__ node_w,
    const float* __restrict__ node_b, ushort_t* __restrict__ xb,
    float* __restrict__ probs, ushort_t* __restrict__ hp) {
  const int wid = threadIdx.x >> 6, lane = threadIdx.x & 63;
  const int t = blockIdx.x * 4 + wid;
  const float* xr = x + (size_t)t * K1;
  float xv[16];
#pragma unroll
  for (int j = 0; j < 4; ++j) {
    float4 v = *(const float4*)(xr + j * 256 + lane * 4);
    xv[4*j+0] = v.x; xv[4*j+1] = v.y; xv[4*j+2] = v.z; xv[4*j+3] = v.w;
  }
  ushort_t* xbr = xb + (size_t)t * K1;
#pragma unroll
  for (int j = 0; j < 4; ++j) {
    ushort4 o;
    o.x = f2bf(xv[4*j+0]); o.y = f2bf(xv[4*j+1]);
    o.z = f2bf(xv[4*j+2]); o.w = f2bf(xv[4*j+3]);
    *(ushort4*)(xbr + j * 256 + lane * 4) = o;
  }
  float c[15];
#pragma unroll
  for (int n = 0; n < 15; ++n) {
    float s = 0.f;
    const float* wr = node_w + n * K1;
#pragma unroll
    for (int j = 0; j < 4; ++j) {
      float4 w = *(const float4*)(wr + j * 256 + lane * 4);
      s += xv[4*j+0]*w.x + xv[4*j+1]*w.y + xv[4*j+2]*w.z + xv[4*j+3]*w.w;
    }
#pragma unroll
    for (int off = 32; off > 0; off >>= 1) s += __shfl_xor(s, off);
    float z = s + node_b[n];
    c[n] = 1.f / (1.f + __expf(-z));
  }
  if (lane < 16) {
    float p = 1.f;
#pragma unroll
    for (int m = 0; m < 4; ++m) {
      int jm = lane >> (4 - m);
      int node = (1 << m) - 1 + jm;
      int bit = (lane >> (3 - m)) & 1;
      p *= bit ? (1.f - c[node]) : c[node];
    }
    probs[t * 16 + lane] = p;
    hp[(size_t)t * K2 + 4096 + lane] = f2bf(p);
  }
  if (lane < 48) hp[(size_t)t * K2 + 4112 + lane] = 0;
}

// ---------------- w1 (16,1024,256) -> w1t (4096 x 1024) bf16 ----------------
__global__ __launch_bounds__(256) void k_w1t(const float* __restrict__ w1,
                                             ushort_t* __restrict__ w1t) {
  __shared__ ushort_t tile[64][68];
  const int b = blockIdx.x;
  const int l = b >> 6, rem = b & 63;
  const int kt = rem >> 2, ht = rem & 3;
  const float* in = w1 + (size_t)l * K1 * 256;
  const int tr = threadIdx.x >> 4;
  const int tc = (threadIdx.x & 15) * 4;
#pragma unroll
  for (int rr = 0; rr < 4; ++rr) {
    int r = tr + rr * 16;
    float4 v = *(const float4*)(in + (size_t)(kt * 64 + r) * 256 + ht * 64 + tc);
    tile[r][tc+0] = f2bf(v.x); tile[r][tc+1] = f2bf(v.y);
    tile[r][tc+2] = f2bf(v.z); tile[r][tc+3] = f2bf(v.w);
  }
  __syncthreads();
#pragma unroll
  for (int rr = 0; rr < 4; ++rr) {
    int oh = tr + rr * 16;
    ushort4 o;
    o.x = tile[tc+0][oh]; o.y = tile[tc+1][oh];
    o.z = tile[tc+2][oh]; o.w = tile[tc+3][oh];
    *(ushort4*)(w1t + (size_t)(l * 256 + ht * 64 + oh) * K1 + kt * 64 + tc) = o;
  }
}

// ---------------- w2 (16,256,1024) -> w2t (1024 x 4160) bf16 ----------------
__global__ __launch_bounds__(256) void k_w2t(const float* __restrict__ w2,
                                             ushort_t* __restrict__ w2t) {
  __shared__ ushort_t tile[64][68];
  const int b = blockIdx.x;
  const int l = b >> 6, rem = b & 63;
  const int ht = rem >> 4, dt = rem & 15;
  const float* in = w2 + (size_t)l * 256 * N2;
  const int tr = threadIdx.x >> 4;
  const int tc = (threadIdx.x & 15) * 4;
#pragma unroll
  for (int rr = 0; rr < 4; ++rr) {
    int r = tr + rr * 16;
    float4 v = *(const float4*)(in + (size_t)(ht * 64 + r) * N2 + dt * 64 + tc);
    tile[r][tc+0] = f2bf(v.x); tile[r][tc+1] = f2bf(v.y);
    tile[r][tc+2] = f2bf(v.z); tile[r][tc+3] = f2bf(v.w);
  }
  __syncthreads();
#pragma unroll
  for (int rr = 0; rr < 4; ++rr) {
    int od = tr + rr * 16;
    ushort4 o;
    o.x = tile[tc+0][od]; o.y = tile[tc+1][od];
    o.z = tile[tc+2][od]; o.w = tile[tc+3][od];
    *(ushort4*)(w2t + (size_t)(dt * 64 + od) * K2 + l * 256 + ht * 64 + tc) = o;
  }
}

__global__ __launch_bounds__(256) void k_b2pad(const float* __restrict__ b2,
                                               ushort_t* __restrict__ w2t) {
  int tid = blockIdx.x * 256 + threadIdx.x;
  int d = tid >> 6, cc = tid & 63;
  float v = (cc < 16) ? b2[cc * N2 + d] : 0.f;
  w2t[(size_t)d * K2 + 4096 + cc] = f2bf(v);
}

// ---------------- 256xBN deep-pipelined MFMA GEMM (m201-style phases) -------
// Per phase: {ds_reads; SB(0x7); stage(1 half-tile); s_barrier; setprio(1);
// 16 MFMA; setprio(0); [vmcnt(6|4)+SB(0) at K-tile end]; s_barrier}.
// No other sched fences: ds_reads of phase p+1 may hoist into phase p's MFMA
// cluster (barriers are NoMem to the scheduler); safety: reads pinned before
// consumer MFMA by data deps, stage-writes land >=200cyc post-issue and are
// separated from conflicting reads by a drained barrier, vmcnt asm keeps the
// "memory" clobber as the tile-boundary fence.
template <int NT, int LDA, int LDB, int BN, int MODE>
__global__ __launch_bounds__(512, 2) void k_gemm8(
    const ushort_t* __restrict__ A, const ushort_t* __restrict__ Bt,
    const float* __restrict__ probs, const float* __restrict__ b1,
    ushort_t* __restrict__ hp, float* __restrict__ out, int ntn) {
  constexpr int BHR = BN / 2;                 // B half rows
  constexpr int WN = (BN == 256) ? 4 : 2;
  constexpr int WM = 8 / WN;
  constexpr int FH = 128 / (WM * 16);         // m-frags per half per wave
  constexpr int PHN = (BN == 256) ? 4 : 2;    // phases per K-tile
  constexpr int ABYTES = 128 * 128;
  constexpr int BBYTES = BHR * 128;

  extern __shared__ char lds[];
  const int tid = threadIdx.x;
  int bid = blockIdx.x;
  const int nwg = gridDim.x;                  // divisible by 8
  bid = (bid & 7) * (nwg >> 3) + (bid >> 3);  // XCD swizzle (bijective)
  const int bm = bid / ntn, bn = bid % ntn;

  const int wid = tid >> 6, lane = tid & 63;
  const int widM = wid / WN, widN = wid % WN;
  const int wmBase = widM * (FH * 16);
  const int wn = widN * 64;
  const int lr = lane & 15, g = lane >> 4;

  const ushort_t* Ag = A + (size_t)bm * 256 * LDA;
  const ushort_t* Bg = Bt + (size_t)bn * BN * LDB;

  const int srow = tid >> 3;
  const int scol = ((tid & 7) << 4) ^ ((srow & 7) << 4);

  auto stageA = [&](int buf, int half, int kt) {
    const ushort_t* src = Ag + (size_t)(half * 128) * LDA + kt * 64;
    char* dst = lds + (buf * 2 + half) * ABYTES + tid * 16;
#pragma unroll
    for (int r = 0; r < 2; ++r)
      gload16((const char*)(src + (size_t)(srow + r * 64) * LDA) + scol,
              dst + r * 8192);
  };
  auto stageB = [&](int buf, int half, int kt) {
    const ushort_t* src = Bg + (size_t)(half * BHR) * LDB + kt * 64;
    char* dst = lds + 4 * ABYTES + (buf * 2 + half) * BBYTES + tid * 16;
#pragma unroll
    for (int r = 0; r < BHR / 64; ++r)
      gload16((const char*)(src + (size_t)(srow + r * 64) * LDB) + scol,
              dst + r * 8192);
  };
  auto rdA = [&](int buf, int half, int i, int kk) -> bf16x8 {
    int r = wmBase + i * 16 + lr;
    int off = r * 128 + (((kk * 4 + g) ^ (lr & 7)) << 4);
    return *(const bf16x8*)(lds + (buf * 2 + half) * ABYTES + off);
  };
  auto rdB = [&](int buf, int j, int kk) -> bf16x8 {
    int nr = wn + j * 16;
    int half = (nr >= BHR) ? 1 : 0;
    int r = (nr & (BHR - 1)) + lr;
    int off = r * 128 + (((kk * 4 + g) ^ (lr & 7)) << 4);
    return *(const bf16x8*)(lds + 4 * ABYTES + (buf * 2 + half) * BBYTES + off);
  };

  f32x4 acc[2 * FH][4];
#pragma unroll
  for (int i = 0; i < 2 * FH; ++i)
#pragma unroll
    for (int j = 0; j < 4; ++j) acc[i][j] = (f32x4){0.f, 0.f, 0.f, 0.f};

  // prologue: tile0 fully (oldest), then {A0,B0,B1}(1); A1(1) at kt=0 ph0.
  stageA(0, 0, 0); stageA(0, 1, 0); stageB(0, 0, 0); stageB(0, 1, 0);
  stageA(1, 0, 1); stageB(1, 0, 1); stageB(1, 1, 1);
  if constexpr (BN == 256) asm volatile("s_waitcnt vmcnt(6)" ::: "memory");
  else                     asm volatile("s_waitcnt vmcnt(4)" ::: "memory");
  __builtin_amdgcn_sched_barrier(0);
  __builtin_amdgcn_s_barrier();

#pragma unroll 1
  for (int kt = 0; kt < NT; ++kt) {
    const int cur = kt & 1;
    bf16x8 bfr[2][4];
#pragma unroll
    for (int ph = 0; ph < PHN; ++ph) {
      constexpr int KKN = (PHN == 4) ? 1 : 2;
      const int q = (PHN == 4) ? (ph >> 1) : ph;
      bf16x8 af[FH][KKN];
#pragma unroll
      for (int kx = 0; kx < KKN; ++kx) {
        const int kk = (PHN == 4) ? (ph & 1) : kx;
#pragma unroll
        for (int i = 0; i < FH; ++i) af[i][kx] = rdA(cur, q, i, kk);
        if (q == 0) {
#pragma unroll
          for (int j = 0; j < 4; ++j) bfr[kk][j] = rdB(cur, j, kk);
        }
      }
      // pin stages below this point (they must not hoist above the reads)
      __builtin_amdgcn_sched_barrier(0x7);
      // stage schedule: ~1 half-tile per phase, spread evenly
      if constexpr (PHN == 4) {
        if (ph == 0 && kt + 1 < NT) stageA(cur ^ 1, 1, kt + 1);
        if (ph == 1 && kt + 2 < NT) stageA(cur, 0, kt + 2);
        if (ph == 2 && kt + 2 < NT) stageB(cur, 0, kt + 2);
        if (ph == 3 && kt + 2 < NT) stageB(cur, 1, kt + 2);
      } else {
        if (ph == 0 && kt + 1 < NT) stageA(cur ^ 1, 1, kt + 1);
        if (ph == 1 && kt + 2 < NT) {
          stageA(cur, 0, kt + 2);
          stageB(cur, 0, kt + 2); stageB(cur, 1, kt + 2);
        }
      }
      __builtin_amdgcn_s_barrier();
      __builtin_amdgcn_s_setprio(1);
#pragma unroll
      for (int kx = 0; kx < KKN; ++kx) {
        const int kk = (PHN == 4) ? (ph & 1) : kx;
#pragma unroll
        for (int i = 0; i < FH; ++i)
#pragma unroll
          for (int j = 0; j < 4; ++j)
            acc[q * FH + i][j] = __builtin_amdgcn_mfma_f32_16x16x32_bf16(
                af[i][kx], bfr[kk][j], acc[q * FH + i][j], 0, 0, 0);
      }
      __builtin_amdgcn_s_setprio(0);
      if (ph == PHN - 1) {
        if (kt + 2 < NT) {
          if constexpr (BN == 256) asm volatile("s_waitcnt vmcnt(6)" ::: "memory");
          else                     asm volatile("s_waitcnt vmcnt(4)" ::: "memory");
          __builtin_amdgcn_sched_barrier(0);
        } else if (kt + 1 < NT) {
          asm volatile("s_waitcnt vmcnt(0)" ::: "memory");
          __builtin_amdgcn_sched_barrier(0);
        }
      }
      __builtin_amdgcn_s_barrier();
    }
  }

  // epilogue: C/D layout col=lane&15, row=(lane>>4)*4+reg
  const int rowb = bm * 256 + wmBase + g * 4;
  const int colb = bn * BN + wn + lr;
  if (MODE == 0) {
    const int leaf = bn;   // BN=256 tile == one leaf
#pragma unroll
    for (int q = 0; q < 2; ++q)
#pragma unroll
      for (int i = 0; i < FH; ++i) {
        int rbase = rowb + q * 128 + i * 16;
        float pm[4];
#pragma unroll
        for (int rg = 0; rg < 4; ++rg)
          pm[rg] = probs[(size_t)(rbase + rg) * 16 + leaf];
#pragma unroll
        for (int j = 0; j < 4; ++j) {
          float bias = b1[colb + j * 16];
#pragma unroll
          for (int rg = 0; rg < 4; ++rg) {
            float v = acc[q * FH + i][j][rg] + bias;
            v = v > 0.f ? v : 0.f;
            v *= pm[rg];
            hp[(size_t)(rbase + rg) * K2 + colb + j * 16] = f2bf(v);
          }
        }
      }
  } else {
#pragma unroll
    for (int q = 0; q < 2; ++q)
#pragma unroll
      for (int i = 0; i < FH; ++i) {
        int rbase = rowb + q * 128 + i * 16;
#pragma unroll
        for (int j = 0; j < 4; ++j)
#pragma unroll
          for (int rg = 0; rg < 4; ++rg)
            out[(size_t)(rbase + rg) * N2 + colb + j * 16] = acc[q * FH + i][j][rg];
      }
  }
}

extern "C" void kernel_launch(void* const* d_in, const int* in_sizes, int n_in,
                              void* d_out, int out_size, void* d_ws, size_t ws_size,
                              hipStream_t stream) {
  const float* x      = (const float*)d_in[0];
  const float* node_w = (const float*)d_in[1];
  const float* node_b = (const float*)d_in[2];
  const float* w1     = (const float*)d_in[3];
  const float* b1     = (const float*)d_in[4];
  const float* w2     = (const float*)d_in[5];
  const float* b2     = (const float*)d_in[6];
  float* out = (float*)d_out;

  char* ws = (char*)d_ws;
  ushort_t* xb    = (ushort_t*)(ws);
  ushort_t* w1t   = (ushort_t*)(ws + 16777216);
  ushort_t* w2t   = (ushort_t*)(ws + 25165824);
  ushort_t* hp    = (ushort_t*)(ws + 33685504);
  float*    probs = (float*)   (ws + 101842944);

  k_probs<<<M_TOK / 4, 256, 0, stream>>>(x, node_w, node_b, xb, probs, hp);
  k_w1t<<<1024, 256, 0, stream>>>(w1, w1t);
  k_w2t<<<1024, 256, 0, stream>>>(w2, w2t);
  k_b2pad<<<256, 256, 0, stream>>>(b2, w2t);
  // GEMM1: 8192x4096, K=1024: 32x16=512 blocks, BN=256, LDS 128 KiB
  k_gemm8<16, K1, K1, 256, 0><<<512, 512, 131072, stream>>>(
      xb, w1t, probs, b1, hp, nullptr, N1 / 256);
  // GEMM2: 8192x1024, K=4160: 32x8=256 blocks, BN=128, LDS 96 KiB
  k_gemm8<65, K2, K2, 128, 1><<<256, 512, 98304, stream>>>(
      hp, w2t, nullptr, nullptr, nullptr, out, N2 / 128);
}

// Round 4
// 184.154 us; speedup vs baseline: 1.3529x; 1.0320x over previous
//
#include <hip/hip_runtime.h>
#include <stdint.h>

typedef unsigned short ushort_t;
typedef __bf16 bf16x8 __attribute__((ext_vector_type(8)));
typedef float f32x4 __attribute__((ext_vector_type(4)));

#define M_TOK 8192
#define K1 1024
#define N1 4096
#define K2 4160   /* 4096 (h) + 16 (probs/b2) + 48 zero-pad -> 65 K-steps of 64 */
#define N2 1024

__device__ __forceinline__ ushort_t f2bf(float f) {
  union { float f; unsigned u; } v; v.f = f;
  unsigned u = v.u;
  u += 0x7FFFu + ((u >> 16) & 1u);   // RNE; inputs finite
  return (ushort_t)(u >> 16);
}

__device__ __forceinline__ void gload16(const void* g, void* l) {
  __builtin_amdgcn_global_load_lds((__attribute__((address_space(1))) void*)g,
                                   (__attribute__((address_space(3))) void*)l,
                                   16, 0, 0);
}

// ---------------- probs + x -> bf16 ----------------
__global__ __launch_bounds__(256) void k_probs(
    const float* __restrict__ x, const float* __restrict__ node_w,
    const float* __restrict__ node_b, ushort_t* __restrict__ xb,
    float* __restrict__ probs, ushort_t* __restrict__ hp) {
  const int wid = threadIdx.x >> 6, lane = threadIdx.x & 63;
  const int t = blockIdx.x * 4 + wid;
  const float* xr = x + (size_t)t * K1;
  float xv[16];
#pragma unroll
  for (int j = 0; j < 4; ++j) {
    float4 v = *(const float4*)(xr + j * 256 + lane * 4);
    xv[4*j+0] = v.x; xv[4*j+1] = v.y; xv[4*j+2] = v.z; xv[4*j+3] = v.w;
  }
  ushort_t* xbr = xb + (size_t)t * K1;
#pragma unroll
  for (int j = 0; j < 4; ++j) {
    ushort4 o;
    o.x = f2bf(xv[4*j+0]); o.y = f2bf(xv[4*j+1]);
    o.z = f2bf(xv[4*j+2]); o.w = f2bf(xv[4*j+3]);
    *(ushort4*)(xbr + j * 256 + lane * 4) = o;
  }
  float c[15];
#pragma unroll
  for (int n = 0; n < 15; ++n) {
    float s = 0.f;
    const float* wr = node_w + n * K1;
#pragma unroll
    for (int j = 0; j < 4; ++j) {
      float4 w = *(const float4*)(wr + j * 256 + lane * 4);
      s += xv[4*j+0]*w.x + xv[4*j+1]*w.y + xv[4*j+2]*w.z + xv[4*j+3]*w.w;
    }
#pragma unroll
    for (int off = 32; off > 0; off >>= 1) s += __shfl_xor(s, off);
    float z = s + node_b[n];
    c[n] = 1.f / (1.f + __expf(-z));
  }
  if (lane < 16) {
    float p = 1.f;
#pragma unroll
    for (int m = 0; m < 4; ++m) {
      int jm = lane >> (4 - m);
      int node = (1 << m) - 1 + jm;
      int bit = (lane >> (3 - m)) & 1;
      p *= bit ? (1.f - c[node]) : c[node];
    }
    probs[t * 16 + lane] = p;
    hp[(size_t)t * K2 + 4096 + lane] = f2bf(p);
  }
  if (lane < 48) hp[(size_t)t * K2 + 4112 + lane] = 0;
}

// ---------------- w1 (16,1024,256) -> w1t (4096 x 1024) bf16 ----------------
__global__ __launch_bounds__(256) void k_w1t(const float* __restrict__ w1,
                                             ushort_t* __restrict__ w1t) {
  __shared__ ushort_t tile[64][68];
  const int b = blockIdx.x;
  const int l = b >> 6, rem = b & 63;
  const int kt = rem >> 2, ht = rem & 3;
  const float* in = w1 + (size_t)l * K1 * 256;
  const int tr = threadIdx.x >> 4;
  const int tc = (threadIdx.x & 15) * 4;
#pragma unroll
  for (int rr = 0; rr < 4; ++rr) {
    int r = tr + rr * 16;
    float4 v = *(const float4*)(in + (size_t)(kt * 64 + r) * 256 + ht * 64 + tc);
    tile[r][tc+0] = f2bf(v.x); tile[r][tc+1] = f2bf(v.y);
    tile[r][tc+2] = f2bf(v.z); tile[r][tc+3] = f2bf(v.w);
  }
  __syncthreads();
#pragma unroll
  for (int rr = 0; rr < 4; ++rr) {
    int oh = tr + rr * 16;
    ushort4 o;
    o.x = tile[tc+0][oh]; o.y = tile[tc+1][oh];
    o.z = tile[tc+2][oh]; o.w = tile[tc+3][oh];
    *(ushort4*)(w1t + (size_t)(l * 256 + ht * 64 + oh) * K1 + kt * 64 + tc) = o;
  }
}

// ---------------- w2 (16,256,1024) -> w2t (1024 x 4160) bf16 ----------------
__global__ __launch_bounds__(256) void k_w2t(const float* __restrict__ w2,
                                             ushort_t* __restrict__ w2t) {
  __shared__ ushort_t tile[64][68];
  const int b = blockIdx.x;
  const int l = b >> 6, rem = b & 63;
  const int ht = rem >> 4, dt = rem & 15;
  const float* in = w2 + (size_t)l * 256 * N2;
  const int tr = threadIdx.x >> 4;
  const int tc = (threadIdx.x & 15) * 4;
#pragma unroll
  for (int rr = 0; rr < 4; ++rr) {
    int r = tr + rr * 16;
    float4 v = *(const float4*)(in + (size_t)(ht * 64 + r) * N2 + dt * 64 + tc);
    tile[r][tc+0] = f2bf(v.x); tile[r][tc+1] = f2bf(v.y);
    tile[r][tc+2] = f2bf(v.z); tile[r][tc+3] = f2bf(v.w);
  }
  __syncthreads();
#pragma unroll
  for (int rr = 0; rr < 4; ++rr) {
    int od = tr + rr * 16;
    ushort4 o;
    o.x = tile[tc+0][od]; o.y = tile[tc+1][od];
    o.z = tile[tc+2][od]; o.w = tile[tc+3][od];
    *(ushort4*)(w2t + (size_t)(dt * 64 + od) * K2 + l * 256 + ht * 64 + tc) = o;
  }
}

__global__ __launch_bounds__(256) void k_b2pad(const float* __restrict__ b2,
                                               ushort_t* __restrict__ w2t) {
  int tid = blockIdx.x * 256 + threadIdx.x;
  int d = tid >> 6, cc = tid & 63;
  float v = (cc < 16) ? b2[cc * N2 + d] : 0.f;
  w2t[(size_t)d * K2 + 4096 + cc] = f2bf(v);
}

// ---------------- 256xBN MFMA GEMM, 2 barriers per K-tile ----------------
// Per K-tile: half0 {rdA(cur,0) + rdB(all) + stage A(cur^1,1,kt+1); 32 MFMA}
// barrier; half1 {rdA(cur,1) + stage (cur,{A0,B0,B1},kt+2); 32 MFMA};
// vmcnt(KEEP); barrier. Race-free by construction: half1's stages overwrite
// only slots whose last reads (half0, all waves) completed at the mid
// barrier; half0's stage writes slot (cur^1,1), last read before the
// PREVIOUS tile-end barrier. vmcnt(KEEP=half1's load count) at tile end
// drains exactly buf(cur^1)'s tile-(kt+1) data (leftover 6|4 + half0's 2).
// Within each half, compiler interleaves ds_reads/MFMA with fine lgkmcnt(N).
template <int NT, int LDA, int LDB, int BN, int MODE>
__global__ __launch_bounds__(512, 2) void k_gemm8(
    const ushort_t* __restrict__ A, const ushort_t* __restrict__ Bt,
    const float* __restrict__ probs, const float* __restrict__ b1,
    ushort_t* __restrict__ hp, float* __restrict__ out, int ntn) {
  constexpr int BHR = BN / 2;                 // B half rows
  constexpr int WN = (BN == 256) ? 4 : 2;
  constexpr int WM = 8 / WN;
  constexpr int FH = 128 / (WM * 16);         // m-frags per half per wave
  constexpr int ABYTES = 128 * 128;
  constexpr int BBYTES = BHR * 128;
  constexpr int KEEP = 2 + 2 * (BHR / 64);    // half1 loads: A0 + B0 + B1

  extern __shared__ char lds[];
  const int tid = threadIdx.x;
  int bid = blockIdx.x;
  const int nwg = gridDim.x;                  // divisible by 8
  bid = (bid & 7) * (nwg >> 3) + (bid >> 3);  // XCD swizzle (bijective)
  const int bm = bid / ntn, bn = bid % ntn;

  const int wid = tid >> 6, lane = tid & 63;
  const int widM = wid / WN, widN = wid % WN;
  const int wmBase = widM * (FH * 16);
  const int wn = widN * 64;
  const int lr = lane & 15, g = lane >> 4;

  const ushort_t* Ag = A + (size_t)bm * 256 * LDA;
  const ushort_t* Bg = Bt + (size_t)bn * BN * LDB;

  const int srow = tid >> 3;
  const int scol = ((tid & 7) << 4) ^ ((srow & 7) << 4);

  auto stageA = [&](int buf, int half, int kt) {
    const ushort_t* src = Ag + (size_t)(half * 128) * LDA + kt * 64;
    char* dst = lds + (buf * 2 + half) * ABYTES + tid * 16;
#pragma unroll
    for (int r = 0; r < 2; ++r)
      gload16((const char*)(src + (size_t)(srow + r * 64) * LDA) + scol,
              dst + r * 8192);
  };
  auto stageB = [&](int buf, int half, int kt) {
    const ushort_t* src = Bg + (size_t)(half * BHR) * LDB + kt * 64;
    char* dst = lds + 4 * ABYTES + (buf * 2 + half) * BBYTES + tid * 16;
#pragma unroll
    for (int r = 0; r < BHR / 64; ++r)
      gload16((const char*)(src + (size_t)(srow + r * 64) * LDB) + scol,
              dst + r * 8192);
  };
  auto rdA = [&](int buf, int half, int i, int kk) -> bf16x8 {
    int r = wmBase + i * 16 + lr;
    int off = r * 128 + (((kk * 4 + g) ^ (lr & 7)) << 4);
    return *(const bf16x8*)(lds + (buf * 2 + half) * ABYTES + off);
  };
  auto rdB = [&](int buf, int j, int kk) -> bf16x8 {
    int nr = wn + j * 16;
    int half = (nr >= BHR) ? 1 : 0;
    int r = (nr & (BHR - 1)) + lr;
    int off = r * 128 + (((kk * 4 + g) ^ (lr & 7)) << 4);
    return *(const bf16x8*)(lds + 4 * ABYTES + (buf * 2 + half) * BBYTES + off);
  };

  f32x4 acc[2 * FH][4];
#pragma unroll
  for (int i = 0; i < 2 * FH; ++i)
#pragma unroll
    for (int j = 0; j < 4; ++j) acc[i][j] = (f32x4){0.f, 0.f, 0.f, 0.f};

  // prologue: buf0 full (8|6 loads, oldest), then buf1 {A0,B0,B1}.
  stageA(0, 0, 0); stageA(0, 1, 0); stageB(0, 0, 0); stageB(0, 1, 0);
  stageA(1, 0, 1); stageB(1, 0, 1); stageB(1, 1, 1);
  {
    constexpr int kp = KEEP;
    if constexpr (kp == 6) asm volatile("s_waitcnt vmcnt(6)" ::: "memory");
    else                   asm volatile("s_waitcnt vmcnt(4)" ::: "memory");
  }
  __builtin_amdgcn_sched_barrier(0);
  __builtin_amdgcn_s_barrier();
  __builtin_amdgcn_sched_barrier(0);

#pragma unroll 1
  for (int kt = 0; kt < NT; ++kt) {
    const int cur = kt & 1;
    bf16x8 bfr[2][4];

    // ---------------- half 0 (A half 0, all B) ----------------
    {
      bf16x8 a0[FH][2];
#pragma unroll
      for (int kk = 0; kk < 2; ++kk) {
#pragma unroll
        for (int i = 0; i < FH; ++i) a0[i][kk] = rdA(cur, 0, i, kk);
#pragma unroll
        for (int j = 0; j < 4; ++j) bfr[kk][j] = rdB(cur, j, kk);
      }
      if (kt + 1 < NT) stageA(cur ^ 1, 1, kt + 1);
      __builtin_amdgcn_s_setprio(1);
#pragma unroll
      for (int kk = 0; kk < 2; ++kk)
#pragma unroll
        for (int i = 0; i < FH; ++i)
#pragma unroll
          for (int j = 0; j < 4; ++j)
            acc[i][j] = __builtin_amdgcn_mfma_f32_16x16x32_bf16(
                a0[i][kk], bfr[kk][j], acc[i][j], 0, 0, 0);
      __builtin_amdgcn_s_setprio(0);
    }
    __builtin_amdgcn_s_barrier();
    __builtin_amdgcn_sched_barrier(0);

    // ---------------- half 1 (A half 1, reuse bfr) ----------------
    {
      bf16x8 a1[FH][2];
#pragma unroll
      for (int kk = 0; kk < 2; ++kk)
#pragma unroll
        for (int i = 0; i < FH; ++i) a1[i][kk] = rdA(cur, 1, i, kk);
      if (kt + 2 < NT) {
        stageA(cur, 0, kt + 2);
        stageB(cur, 0, kt + 2);
        stageB(cur, 1, kt + 2);
      }
      __builtin_amdgcn_s_setprio(1);
#pragma unroll
      for (int kk = 0; kk < 2; ++kk)
#pragma unroll
        for (int i = 0; i < FH; ++i)
#pragma unroll
          for (int j = 0; j < 4; ++j)
            acc[FH + i][j] = __builtin_amdgcn_mfma_f32_16x16x32_bf16(
                a1[i][kk], bfr[kk][j], acc[FH + i][j], 0, 0, 0);
      __builtin_amdgcn_s_setprio(0);
    }
    if (kt + 2 < NT) {
      constexpr int kp = KEEP;
      if constexpr (kp == 6) asm volatile("s_waitcnt vmcnt(6)" ::: "memory");
      else                   asm volatile("s_waitcnt vmcnt(4)" ::: "memory");
      __builtin_amdgcn_sched_barrier(0);
    } else if (kt + 1 < NT) {
      asm volatile("s_waitcnt vmcnt(0)" ::: "memory");
      __builtin_amdgcn_sched_barrier(0);
    }
    __builtin_amdgcn_s_barrier();
    __builtin_amdgcn_sched_barrier(0);
  }

  // epilogue: C/D layout col=lane&15, row=(lane>>4)*4+reg
  const int rowb = bm * 256 + wmBase + g * 4;
  const int colb = bn * BN + wn + lr;
  if (MODE == 0) {
    const int leaf = bn;   // BN=256 tile == one leaf
#pragma unroll
    for (int q = 0; q < 2; ++q)
#pragma unroll
      for (int i = 0; i < FH; ++i) {
        int rbase = rowb + q * 128 + i * 16;
        float pm[4];
#pragma unroll
        for (int rg = 0; rg < 4; ++rg)
          pm[rg] = probs[(size_t)(rbase + rg) * 16 + leaf];
#pragma unroll
        for (int j = 0; j < 4; ++j) {
          float bias = b1[colb + j * 16];
#pragma unroll
          for (int rg = 0; rg < 4; ++rg) {
            float v = acc[q * FH + i][j][rg] + bias;
            v = v > 0.f ? v : 0.f;
            v *= pm[rg];
            hp[(size_t)(rbase + rg) * K2 + colb + j * 16] = f2bf(v);
          }
        }
      }
  } else {
#pragma unroll
    for (int q = 0; q < 2; ++q)
#pragma unroll
      for (int i = 0; i < FH; ++i) {
        int rbase = rowb + q * 128 + i * 16;
#pragma unroll
        for (int j = 0; j < 4; ++j)
#pragma unroll
          for (int rg = 0; rg < 4; ++rg)
            out[(size_t)(rbase + rg) * N2 + colb + j * 16] = acc[q * FH + i][j][rg];
      }
  }
}

extern "C" void kernel_launch(void* const* d_in, const int* in_sizes, int n_in,
                              void* d_out, int out_size, void* d_ws, size_t ws_size,
                              hipStream_t stream) {
  const float* x      = (const float*)d_in[0];
  const float* node_w = (const float*)d_in[1];
  const float* node_b = (const float*)d_in[2];
  const float* w1     = (const float*)d_in[3];
  const float* b1     = (const float*)d_in[4];
  const float* w2     = (const float*)d_in[5];
  const float* b2     = (const float*)d_in[6];
  float* out = (float*)d_out;

  char* ws = (char*)d_ws;
  ushort_t* xb    = (ushort_t*)(ws);
  ushort_t* w1t   = (ushort_t*)(ws + 16777216);
  ushort_t* w2t   = (ushort_t*)(ws + 25165824);
  ushort_t* hp    = (ushort_t*)(ws + 33685504);
  float*    probs = (float*)   (ws + 101842944);

  k_probs<<<M_TOK / 4, 256, 0, stream>>>(x, node_w, node_b, xb, probs, hp);
  k_w1t<<<1024, 256, 0, stream>>>(w1, w1t);
  k_w2t<<<1024, 256, 0, stream>>>(w2, w2t);
  k_b2pad<<<256, 256, 0, stream>>>(b2, w2t);
  // GEMM1: 8192x4096, K=1024: 32x16=512 blocks, BN=256, LDS 128 KiB
  k_gemm8<16, K1, K1, 256, 0><<<512, 512, 131072, stream>>>(
      xb, w1t, probs, b1, hp, nullptr, N1 / 256);
  // GEMM2: 8192x1024, K=4160: 32x8=256 blocks, BN=128, LDS 96 KiB
  k_gemm8<65, K2, K2, 128, 1><<<256, 512, 98304, stream>>>(
      hp, w2t, nullptr, nullptr, nullptr, out, N2 / 128);
}

// Round 5
// 179.286 us; speedup vs baseline: 1.3896x; 1.0272x over previous
//
#include <hip/hip_runtime.h>
#include <stdint.h>

typedef unsigned short ushort_t;
typedef __bf16 bf16x8 __attribute__((ext_vector_type(8)));
typedef float f32x4 __attribute__((ext_vector_type(4)));

#define M_TOK 8192
#define K1 1024
#define N1 4096
#define K2 4160   /* 4096 (h) + 16 (probs/b2) + 48 zero-pad -> 65 K-steps of 64 */
#define N2 1024

#define SGB(m, n) __builtin_amdgcn_sched_group_barrier((m), (n), 0)
#define SGB_DS   0x100
#define SGB_MFMA 0x008

__device__ __forceinline__ ushort_t f2bf(float f) {
  union { float f; unsigned u; } v; v.f = f;
  unsigned u = v.u;
  u += 0x7FFFu + ((u >> 16) & 1u);   // RNE; inputs finite
  return (ushort_t)(u >> 16);
}

__device__ __forceinline__ void gload16(const void* g, void* l) {
  __builtin_amdgcn_global_load_lds((__attribute__((address_space(1))) void*)g,
                                   (__attribute__((address_space(3))) void*)l,
                                   16, 0, 0);
}

// ---------------- probs + x -> bf16 ----------------
__global__ __launch_bounds__(256) void k_probs(
    const float* __restrict__ x, const float* __restrict__ node_w,
    const float* __restrict__ node_b, ushort_t* __restrict__ xb,
    float* __restrict__ probs, ushort_t* __restrict__ hp) {
  const int wid = threadIdx.x >> 6, lane = threadIdx.x & 63;
  const int t = blockIdx.x * 4 + wid;
  const float* xr = x + (size_t)t * K1;
  float xv[16];
#pragma unroll
  for (int j = 0; j < 4; ++j) {
    float4 v = *(const float4*)(xr + j * 256 + lane * 4);
    xv[4*j+0] = v.x; xv[4*j+1] = v.y; xv[4*j+2] = v.z; xv[4*j+3] = v.w;
  }
  ushort_t* xbr = xb + (size_t)t * K1;
#pragma unroll
  for (int j = 0; j < 4; ++j) {
    ushort4 o;
    o.x = f2bf(xv[4*j+0]); o.y = f2bf(xv[4*j+1]);
    o.z = f2bf(xv[4*j+2]); o.w = f2bf(xv[4*j+3]);
    *(ushort4*)(xbr + j * 256 + lane * 4) = o;
  }
  float c[15];
#pragma unroll
  for (int n = 0; n < 15; ++n) {
    float s = 0.f;
    const float* wr = node_w + n * K1;
#pragma unroll
    for (int j = 0; j < 4; ++j) {
      float4 w = *(const float4*)(wr + j * 256 + lane * 4);
      s += xv[4*j+0]*w.x + xv[4*j+1]*w.y + xv[4*j+2]*w.z + xv[4*j+3]*w.w;
    }
#pragma unroll
    for (int off = 32; off > 0; off >>= 1) s += __shfl_xor(s, off);
    float z = s + node_b[n];
    c[n] = 1.f / (1.f + __expf(-z));
  }
  if (lane < 16) {
    float p = 1.f;
#pragma unroll
    for (int m = 0; m < 4; ++m) {
      int jm = lane >> (4 - m);
      int node = (1 << m) - 1 + jm;
      int bit = (lane >> (3 - m)) & 1;
      p *= bit ? (1.f - c[node]) : c[node];
    }
    probs[t * 16 + lane] = p;
    hp[(size_t)t * K2 + 4096 + lane] = f2bf(p);
  }
  if (lane < 48) hp[(size_t)t * K2 + 4112 + lane] = 0;
}

// ---------------- fused weight prep: w1t | w2t | b2pad ----------------
// b<1024: w1t[l*256+h][k] = w1[l][k][h]
// b<2048: w2t[d][l*256+h] = w2[l][h][d]
// else  : b2 rows + zero pad into w2t cols 4096..4159
__global__ __launch_bounds__(256) void k_wprep(
    const float* __restrict__ w1, const float* __restrict__ w2,
    const float* __restrict__ b2, ushort_t* __restrict__ w1t,
    ushort_t* __restrict__ w2t) {
  __shared__ ushort_t tile[64][68];
  const int b = blockIdx.x;
  const int tr = threadIdx.x >> 4;
  const int tc = (threadIdx.x & 15) * 4;
  if (b < 1024) {
    const int l = b >> 6, rem = b & 63;
    const int kt = rem >> 2, ht = rem & 3;
    const float* in = w1 + (size_t)l * K1 * 256;
#pragma unroll
    for (int rr = 0; rr < 4; ++rr) {
      int r = tr + rr * 16;
      float4 v = *(const float4*)(in + (size_t)(kt * 64 + r) * 256 + ht * 64 + tc);
      tile[r][tc+0] = f2bf(v.x); tile[r][tc+1] = f2bf(v.y);
      tile[r][tc+2] = f2bf(v.z); tile[r][tc+3] = f2bf(v.w);
    }
    __syncthreads();
#pragma unroll
    for (int rr = 0; rr < 4; ++rr) {
      int oh = tr + rr * 16;
      ushort4 o;
      o.x = tile[tc+0][oh]; o.y = tile[tc+1][oh];
      o.z = tile[tc+2][oh]; o.w = tile[tc+3][oh];
      *(ushort4*)(w1t + (size_t)(l * 256 + ht * 64 + oh) * K1 + kt * 64 + tc) = o;
    }
  } else if (b < 2048) {
    const int bb = b - 1024;
    const int l = bb >> 6, rem = bb & 63;
    const int ht = rem >> 4, dt = rem & 15;
    const float* in = w2 + (size_t)l * 256 * N2;
#pragma unroll
    for (int rr = 0; rr < 4; ++rr) {
      int r = tr + rr * 16;
      float4 v = *(const float4*)(in + (size_t)(ht * 64 + r) * N2 + dt * 64 + tc);
      tile[r][tc+0] = f2bf(v.x); tile[r][tc+1] = f2bf(v.y);
      tile[r][tc+2] = f2bf(v.z); tile[r][tc+3] = f2bf(v.w);
    }
    __syncthreads();
#pragma unroll
    for (int rr = 0; rr < 4; ++rr) {
      int od = tr + rr * 16;
      ushort4 o;
      o.x = tile[tc+0][od]; o.y = tile[tc+1][od];
      o.z = tile[tc+2][od]; o.w = tile[tc+3][od];
      *(ushort4*)(w2t + (size_t)(dt * 64 + od) * K2 + l * 256 + ht * 64 + tc) = o;
    }
  } else {
    int tid = (b - 2048) * 256 + threadIdx.x;   // 1024 * 64
    int d = tid >> 6, cc = tid & 63;
    float v = (cc < 16) ? b2[cc * N2 + d] : 0.f;
    w2t[(size_t)d * K2 + 4096 + cc] = f2bf(v);
  }
}

// ---------------- 256xBN MFMA GEMM, 2 barriers/K-tile + SGB interleave ------
// Region0 {rdA(cur,0)+rdB(all) | stage A(cur^1,1,kt+1) | 32|16 MFMA half0}
// barrier; Region1 {rdA(cur,1) | stage cur,{A0,B0,B1},kt+2 | 32|16 MFMA
// half1}; vmcnt(KEEP); barrier. Hazards identical to round-4 (verified).
// NEW: sched_group_barrier patterns force DS_READ/MFMA emission interleave
// so the LDS pipe drains under the MFMA burst instead of serializing.
template <int NT, int LDA, int LDB, int BN, int MODE>
__global__ __launch_bounds__(512, 2) void k_gemm8(
    const ushort_t* __restrict__ A, const ushort_t* __restrict__ Bt,
    const float* __restrict__ probs, const float* __restrict__ b1,
    ushort_t* __restrict__ hp, float* __restrict__ out, int ntn) {
  constexpr int BHR = BN / 2;                 // B half rows
  constexpr int WN = (BN == 256) ? 4 : 2;
  constexpr int WM = 8 / WN;
  constexpr int FH = 128 / (WM * 16);         // m-frags per half per wave
  constexpr int ABYTES = 128 * 128;
  constexpr int BBYTES = BHR * 128;
  constexpr int KEEP = 2 + 2 * (BHR / 64);    // region1 loads: A0 + B0 + B1

  extern __shared__ char lds[];
  const int tid = threadIdx.x;
  int bid = blockIdx.x;
  const int nwg = gridDim.x;                  // divisible by 8
  bid = (bid & 7) * (nwg >> 3) + (bid >> 3);  // XCD swizzle (bijective)
  const int bm = bid / ntn, bn = bid % ntn;

  const int wid = tid >> 6, lane = tid & 63;
  const int widM = wid / WN, widN = wid % WN;
  const int wmBase = widM * (FH * 16);
  const int wn = widN * 64;
  const int lr = lane & 15, g = lane >> 4;

  const ushort_t* Ag = A + (size_t)bm * 256 * LDA;
  const ushort_t* Bg = Bt + (size_t)bn * BN * LDB;

  const int srow = tid >> 3;
  const int scol = ((tid & 7) << 4) ^ ((srow & 7) << 4);

  auto stageA = [&](int buf, int half, int kt) {
    const ushort_t* src = Ag + (size_t)(half * 128) * LDA + kt * 64;
    char* dst = lds + (buf * 2 + half) * ABYTES + tid * 16;
#pragma unroll
    for (int r = 0; r < 2; ++r)
      gload16((const char*)(src + (size_t)(srow + r * 64) * LDA) + scol,
              dst + r * 8192);
  };
  auto stageB = [&](int buf, int half, int kt) {
    const ushort_t* src = Bg + (size_t)(half * BHR) * LDB + kt * 64;
    char* dst = lds + 4 * ABYTES + (buf * 2 + half) * BBYTES + tid * 16;
#pragma unroll
    for (int r = 0; r < BHR / 64; ++r)
      gload16((const char*)(src + (size_t)(srow + r * 64) * LDB) + scol,
              dst + r * 8192);
  };
  auto rdA = [&](int buf, int half, int i, int kk) -> bf16x8 {
    int r = wmBase + i * 16 + lr;
    int off = r * 128 + (((kk * 4 + g) ^ (lr & 7)) << 4);
    return *(const bf16x8*)(lds + (buf * 2 + half) * ABYTES + off);
  };
  auto rdB = [&](int buf, int j, int kk) -> bf16x8 {
    int nr = wn + j * 16;
    int half = (nr >= BHR) ? 1 : 0;
    int r = (nr & (BHR - 1)) + lr;
    int off = r * 128 + (((kk * 4 + g) ^ (lr & 7)) << 4);
    return *(const bf16x8*)(lds + 4 * ABYTES + (buf * 2 + half) * BBYTES + off);
  };

  f32x4 acc[2 * FH][4];
#pragma unroll
  for (int i = 0; i < 2 * FH; ++i)
#pragma unroll
    for (int j = 0; j < 4; ++j) acc[i][j] = (f32x4){0.f, 0.f, 0.f, 0.f};

  // prologue: buf0 full (oldest), then buf1 {A0,B0,B1}.
  stageA(0, 0, 0); stageA(0, 1, 0); stageB(0, 0, 0); stageB(0, 1, 0);
  stageA(1, 0, 1); stageB(1, 0, 1); stageB(1, 1, 1);
  if constexpr (KEEP == 6) asm volatile("s_waitcnt vmcnt(6)" ::: "memory");
  else                     asm volatile("s_waitcnt vmcnt(4)" ::: "memory");
  __builtin_amdgcn_sched_barrier(0);
  __builtin_amdgcn_s_barrier();
  __builtin_amdgcn_sched_barrier(0);

#pragma unroll 1
  for (int kt = 0; kt < NT; ++kt) {
    const int cur = kt & 1;
    bf16x8 bfr[2][4];

    // ---------------- region 0 (A half 0, all B) ----------------
    {
      bf16x8 a0[FH][2];
#pragma unroll
      for (int kk = 0; kk < 2; ++kk) {
#pragma unroll
        for (int i = 0; i < FH; ++i) a0[i][kk] = rdA(cur, 0, i, kk);
#pragma unroll
        for (int j = 0; j < 4; ++j) bfr[kk][j] = rdB(cur, j, kk);
      }
      if (kt + 1 < NT) stageA(cur ^ 1, 1, kt + 1);
      __builtin_amdgcn_s_setprio(1);
#pragma unroll
      for (int kk = 0; kk < 2; ++kk)
#pragma unroll
        for (int j = 0; j < 4; ++j)
#pragma unroll
          for (int i = 0; i < FH; ++i)
            acc[i][j] = __builtin_amdgcn_mfma_f32_16x16x32_bf16(
                a0[i][kk], bfr[kk][j], acc[i][j], 0, 0, 0);
      __builtin_amdgcn_s_setprio(0);
      // emission interleave: per kk {DS (FH+1), MFMA FH, (DS1, MFMA FH)x3}
#pragma unroll
      for (int kk = 0; kk < 2; ++kk) {
        SGB(SGB_DS, FH + 1); SGB(SGB_MFMA, FH);
#pragma unroll
        for (int rep = 0; rep < 3; ++rep) { SGB(SGB_DS, 1); SGB(SGB_MFMA, FH); }
      }
    }
    __builtin_amdgcn_s_barrier();
    __builtin_amdgcn_sched_barrier(0);

    // ---------------- region 1 (A half 1, reuse bfr) ----------------
    {
      bf16x8 a1[FH][2];
#pragma unroll
      for (int kk = 0; kk < 2; ++kk)
#pragma unroll
        for (int i = 0; i < FH; ++i) a1[i][kk] = rdA(cur, 1, i, kk);
      if (kt + 2 < NT) {
        stageA(cur, 0, kt + 2);
        stageB(cur, 0, kt + 2);
        stageB(cur, 1, kt + 2);
      }
      __builtin_amdgcn_s_setprio(1);
#pragma unroll
      for (int kk = 0; kk < 2; ++kk)
#pragma unroll
        for (int j = 0; j < 4; ++j)
#pragma unroll
          for (int i = 0; i < FH; ++i)
            acc[FH + i][j] = __builtin_amdgcn_mfma_f32_16x16x32_bf16(
                a1[i][kk], bfr[kk][j], acc[FH + i][j], 0, 0, 0);
      __builtin_amdgcn_s_setprio(0);
      // emission interleave: per kk {DS FH, MFMA 2*FH, MFMA 2*FH}
#pragma unroll
      for (int kk = 0; kk < 2; ++kk) {
        SGB(SGB_DS, FH); SGB(SGB_MFMA, 2 * FH); SGB(SGB_MFMA, 2 * FH);
      }
    }
    if (kt + 2 < NT) {
      if constexpr (KEEP == 6) asm volatile("s_waitcnt vmcnt(6)" ::: "memory");
      else                     asm volatile("s_waitcnt vmcnt(4)" ::: "memory");
      __builtin_amdgcn_sched_barrier(0);
    } else if (kt + 1 < NT) {
      asm volatile("s_waitcnt vmcnt(0)" ::: "memory");
      __builtin_amdgcn_sched_barrier(0);
    }
    __builtin_amdgcn_s_barrier();
    __builtin_amdgcn_sched_barrier(0);
  }

  // epilogue: C/D layout col=lane&15, row=(lane>>4)*4+reg
  const int rowb = bm * 256 + wmBase + g * 4;
  const int colb = bn * BN + wn + lr;
  if (MODE == 0) {
    const int leaf = bn;   // BN=256 tile == one leaf
#pragma unroll
    for (int q = 0; q < 2; ++q)
#pragma unroll
      for (int i = 0; i < FH; ++i) {
        int rbase = rowb + q * 128 + i * 16;
        float pm[4];
#pragma unroll
        for (int rg = 0; rg < 4; ++rg)
          pm[rg] = probs[(size_t)(rbase + rg) * 16 + leaf];
#pragma unroll
        for (int j = 0; j < 4; ++j) {
          float bias = b1[colb + j * 16];
#pragma unroll
          for (int rg = 0; rg < 4; ++rg) {
            float v = acc[q * FH + i][j][rg] + bias;
            v = v > 0.f ? v : 0.f;
            v *= pm[rg];
            hp[(size_t)(rbase + rg) * K2 + colb + j * 16] = f2bf(v);
          }
        }
      }
  } else {
#pragma unroll
    for (int q = 0; q < 2; ++q)
#pragma unroll
      for (int i = 0; i < FH; ++i) {
        int rbase = rowb + q * 128 + i * 16;
#pragma unroll
        for (int j = 0; j < 4; ++j)
#pragma unroll
          for (int rg = 0; rg < 4; ++rg)
            out[(size_t)(rbase + rg) * N2 + colb + j * 16] = acc[q * FH + i][j][rg];
      }
  }
}

extern "C" void kernel_launch(void* const* d_in, const int* in_sizes, int n_in,
                              void* d_out, int out_size, void* d_ws, size_t ws_size,
                              hipStream_t stream) {
  const float* x      = (const float*)d_in[0];
  const float* node_w = (const float*)d_in[1];
  const float* node_b = (const float*)d_in[2];
  const float* w1     = (const float*)d_in[3];
  const float* b1     = (const float*)d_in[4];
  const float* w2     = (const float*)d_in[5];
  const float* b2     = (const float*)d_in[6];
  float* out = (float*)d_out;

  char* ws = (char*)d_ws;
  ushort_t* xb    = (ushort_t*)(ws);
  ushort_t* w1t   = (ushort_t*)(ws + 16777216);
  ushort_t* w2t   = (ushort_t*)(ws + 25165824);
  ushort_t* hp    = (ushort_t*)(ws + 33685504);
  float*    probs = (float*)   (ws + 101842944);

  k_probs<<<M_TOK / 4, 256, 0, stream>>>(x, node_w, node_b, xb, probs, hp);
  k_wprep<<<2304, 256, 0, stream>>>(w1, w2, b2, w1t, w2t);
  // GEMM1: 8192x4096, K=1024: 32x16=512 blocks, BN=256, LDS 128 KiB
  k_gemm8<16, K1, K1, 256, 0><<<512, 512, 131072, stream>>>(
      xb, w1t, probs, b1, hp, nullptr, N1 / 256);
  // GEMM2: 8192x1024, K=4160: 32x8=256 blocks, BN=128, LDS 96 KiB
  k_gemm8<65, K2, K2, 128, 1><<<256, 512, 98304, stream>>>(
      hp, w2t, nullptr, nullptr, nullptr, out, N2 / 128);
}

// Round 6
// 169.003 us; speedup vs baseline: 1.4742x; 1.0608x over previous
//
#include <hip/hip_runtime.h>
#include <stdint.h>

typedef unsigned short ushort_t;
typedef __bf16 bf16x8 __attribute__((ext_vector_type(8)));
typedef float f32x4 __attribute__((ext_vector_type(4)));

#define M_TOK 8192
#define K1 1024
#define N1 4096
#define K2 4160   /* 4096 (h) + 16 (probs/b2) + 48 zero-pad -> 65 K-steps of 64 */
#define N2 1024

template <int V> struct ic { static constexpr int value = V; };

__device__ __forceinline__ ushort_t f2bf(float f) {
  union { float f; unsigned u; } v; v.f = f;
  unsigned u = v.u;
  u += 0x7FFFu + ((u >> 16) & 1u);   // RNE; inputs finite
  return (ushort_t)(u >> 16);
}

__device__ __forceinline__ void gload16(const void* g, void* l) {
  __builtin_amdgcn_global_load_lds((__attribute__((address_space(1))) void*)g,
                                   (__attribute__((address_space(3))) void*)l,
                                   16, 0, 0);
}

// ---------------- merged prep: wprep (blocks 0..2303) + probs (2304..4351) --
__global__ __launch_bounds__(256) void k_prep(
    const float* __restrict__ x, const float* __restrict__ node_w,
    const float* __restrict__ node_b, const float* __restrict__ w1,
    const float* __restrict__ w2, const float* __restrict__ b2,
    ushort_t* __restrict__ xb, float* __restrict__ probs,
    ushort_t* __restrict__ w1t, ushort_t* __restrict__ w2t,
    ushort_t* __restrict__ hp) {
  __shared__ ushort_t tile[64][68];
  const int b = blockIdx.x;
  if (b < 1024) {
    // w1t[l*256+h][k] = w1[l][k][h]
    const int tr = threadIdx.x >> 4, tc = (threadIdx.x & 15) * 4;
    const int l = b >> 6, rem = b & 63;
    const int kt = rem >> 2, ht = rem & 3;
    const float* in = w1 + (size_t)l * K1 * 256;
#pragma unroll
    for (int rr = 0; rr < 4; ++rr) {
      int r = tr + rr * 16;
      float4 v = *(const float4*)(in + (size_t)(kt * 64 + r) * 256 + ht * 64 + tc);
      tile[r][tc+0] = f2bf(v.x); tile[r][tc+1] = f2bf(v.y);
      tile[r][tc+2] = f2bf(v.z); tile[r][tc+3] = f2bf(v.w);
    }
    __syncthreads();
#pragma unroll
    for (int rr = 0; rr < 4; ++rr) {
      int oh = tr + rr * 16;
      ushort4 o;
      o.x = tile[tc+0][oh]; o.y = tile[tc+1][oh];
      o.z = tile[tc+2][oh]; o.w = tile[tc+3][oh];
      *(ushort4*)(w1t + (size_t)(l * 256 + ht * 64 + oh) * K1 + kt * 64 + tc) = o;
    }
  } else if (b < 2048) {
    // w2t[d][l*256+h] = w2[l][h][d]
    const int tr = threadIdx.x >> 4, tc = (threadIdx.x & 15) * 4;
    const int bb = b - 1024;
    const int l = bb >> 6, rem = bb & 63;
    const int ht = rem >> 4, dt = rem & 15;
    const float* in = w2 + (size_t)l * 256 * N2;
#pragma unroll
    for (int rr = 0; rr < 4; ++rr) {
      int r = tr + rr * 16;
      float4 v = *(const float4*)(in + (size_t)(ht * 64 + r) * N2 + dt * 64 + tc);
      tile[r][tc+0] = f2bf(v.x); tile[r][tc+1] = f2bf(v.y);
      tile[r][tc+2] = f2bf(v.z); tile[r][tc+3] = f2bf(v.w);
    }
    __syncthreads();
#pragma unroll
    for (int rr = 0; rr < 4; ++rr) {
      int od = tr + rr * 16;
      ushort4 o;
      o.x = tile[tc+0][od]; o.y = tile[tc+1][od];
      o.z = tile[tc+2][od]; o.w = tile[tc+3][od];
      *(ushort4*)(w2t + (size_t)(dt * 64 + od) * K2 + l * 256 + ht * 64 + tc) = o;
    }
  } else if (b < 2304) {
    // b2 rows + zero pad into w2t cols 4096..4159
    int tid = (b - 2048) * 256 + threadIdx.x;   // 1024 * 64
    int d = tid >> 6, cc = tid & 63;
    float v = (cc < 16) ? b2[cc * N2 + d] : 0.f;
    w2t[(size_t)d * K2 + 4096 + cc] = f2bf(v);
  } else {
    // probs + x->bf16; 1 wave per token
    const int wid = threadIdx.x >> 6, lane = threadIdx.x & 63;
    const int t = (b - 2304) * 4 + wid;
    const float* xr = x + (size_t)t * K1;
    float xv[16];
#pragma unroll
    for (int j = 0; j < 4; ++j) {
      float4 v = *(const float4*)(xr + j * 256 + lane * 4);
      xv[4*j+0] = v.x; xv[4*j+1] = v.y; xv[4*j+2] = v.z; xv[4*j+3] = v.w;
    }
    ushort_t* xbr = xb + (size_t)t * K1;
#pragma unroll
    for (int j = 0; j < 4; ++j) {
      ushort4 o;
      o.x = f2bf(xv[4*j+0]); o.y = f2bf(xv[4*j+1]);
      o.z = f2bf(xv[4*j+2]); o.w = f2bf(xv[4*j+3]);
      *(ushort4*)(xbr + j * 256 + lane * 4) = o;
    }
    float c[15];
#pragma unroll
    for (int n = 0; n < 15; ++n) {
      float s = 0.f;
      const float* wr = node_w + n * K1;
#pragma unroll
      for (int j = 0; j < 4; ++j) {
        float4 w = *(const float4*)(wr + j * 256 + lane * 4);
        s += xv[4*j+0]*w.x + xv[4*j+1]*w.y + xv[4*j+2]*w.z + xv[4*j+3]*w.w;
      }
#pragma unroll
      for (int off = 32; off > 0; off >>= 1) s += __shfl_xor(s, off);
      float z = s + node_b[n];
      c[n] = 1.f / (1.f + __expf(-z));
    }
    if (lane < 16) {
      float p = 1.f;
#pragma unroll
      for (int m = 0; m < 4; ++m) {
        int jm = lane >> (4 - m);
        int node = (1 << m) - 1 + jm;
        int bit = (lane >> (3 - m)) & 1;
        p *= bit ? (1.f - c[node]) : c[node];
      }
      probs[t * 16 + lane] = p;
      hp[(size_t)t * K2 + 4096 + lane] = f2bf(p);
    }
    if (lane < 48) hp[(size_t)t * K2 + 4112 + lane] = 0;
  }
}

// ---------------- 256xBN MFMA GEMM, 2 barriers/K-tile, K-loop unroll x2 -----
// Structure identical to round-4 (hazards verified there); NEW: body is
// instantiated with buf index `cur` as a compile-time constant so every
// ds_read / LDS-stage address is base-reg + literal offset (no VALU addr
// math on the issue path).
template <int NT, int LDA, int LDB, int BN, int MODE>
__global__ __launch_bounds__(512, 2) void k_gemm8(
    const ushort_t* __restrict__ A, const ushort_t* __restrict__ Bt,
    const float* __restrict__ probs, const float* __restrict__ b1,
    ushort_t* __restrict__ hp, float* __restrict__ out, int ntn) {
  constexpr int BHR = BN / 2;                 // B half rows
  constexpr int WN = (BN == 256) ? 4 : 2;
  constexpr int WM = 8 / WN;
  constexpr int FH = 128 / (WM * 16);         // m-frags per half per wave
  constexpr int ABYTES = 128 * 128;
  constexpr int BBYTES = BHR * 128;
  constexpr int KEEP = 2 + 2 * (BHR / 64);    // region1 loads: A0 + B0 + B1

  extern __shared__ char lds[];
  const int tid = threadIdx.x;
  int bid = blockIdx.x;
  const int nwg = gridDim.x;                  // divisible by 8
  bid = (bid & 7) * (nwg >> 3) + (bid >> 3);  // XCD swizzle (bijective)
  const int bm = bid / ntn, bn = bid % ntn;

  const int wid = tid >> 6, lane = tid & 63;
  const int widM = wid / WN, widN = wid % WN;
  const int wmBase = widM * (FH * 16);
  const int wn = widN * 64;
  const int lr = lane & 15, g = lane >> 4;

  const ushort_t* Ag = A + (size_t)bm * 256 * LDA;
  const ushort_t* Bg = Bt + (size_t)bn * BN * LDB;

  const int srow = tid >> 3;
  const int scol = ((tid & 7) << 4) ^ ((srow & 7) << 4);

  // per-thread staging bases (byte pointers); kt advances by +128 bytes
  const char* pA = (const char*)(Ag + (size_t)srow * LDA) + scol;
  const char* pB = (const char*)(Bg + (size_t)srow * LDB) + scol;

  auto stageA = [&](int buf, int half, int kt) {
    const char* src = pA + (size_t)(half * 128) * (LDA * 2) + kt * 128;
    char* dst = lds + (buf * 2 + half) * ABYTES + tid * 16;
#pragma unroll
    for (int r = 0; r < 2; ++r)
      gload16(src + (size_t)(r * 64) * (LDA * 2), dst + r * 8192);
  };
  auto stageB = [&](int buf, int half, int kt) {
    const char* src = pB + (size_t)(half * BHR) * (LDB * 2) + kt * 128;
    char* dst = lds + 4 * ABYTES + (buf * 2 + half) * BBYTES + tid * 16;
#pragma unroll
    for (int r = 0; r < BHR / 64; ++r)
      gload16(src + (size_t)(r * 64) * (LDB * 2), dst + r * 8192);
  };
  auto rdA = [&](int buf, int half, int i, int kk) -> bf16x8 {
    int r = wmBase + i * 16 + lr;
    int off = r * 128 + (((kk * 4 + g) ^ (lr & 7)) << 4);
    return *(const bf16x8*)(lds + (buf * 2 + half) * ABYTES + off);
  };
  auto rdB = [&](int buf, int j, int kk) -> bf16x8 {
    int nr = wn + j * 16;
    int half = (nr >= BHR) ? 1 : 0;
    int r = (nr & (BHR - 1)) + lr;
    int off = r * 128 + (((kk * 4 + g) ^ (lr & 7)) << 4);
    return *(const bf16x8*)(lds + 4 * ABYTES + (buf * 2 + half) * BBYTES + off);
  };

  f32x4 acc[2 * FH][4];
#pragma unroll
  for (int i = 0; i < 2 * FH; ++i)
#pragma unroll
    for (int j = 0; j < 4; ++j) acc[i][j] = (f32x4){0.f, 0.f, 0.f, 0.f};

  // prologue: buf0 full (oldest), then buf1 {A0,B0,B1}.
  stageA(0, 0, 0); stageA(0, 1, 0); stageB(0, 0, 0); stageB(0, 1, 0);
  stageA(1, 0, 1); stageB(1, 0, 1); stageB(1, 1, 1);
  if constexpr (KEEP == 6) asm volatile("s_waitcnt vmcnt(6)" ::: "memory");
  else                     asm volatile("s_waitcnt vmcnt(4)" ::: "memory");
  __builtin_amdgcn_sched_barrier(0);
  __builtin_amdgcn_s_barrier();
  __builtin_amdgcn_sched_barrier(0);

  auto body = [&](auto CURC, int kt) {
    constexpr int cur = decltype(CURC)::value;
    bf16x8 bfr[2][4];
    // ---------------- region 0 (A half 0, all B) ----------------
    {
      bf16x8 a0[FH][2];
#pragma unroll
      for (int kk = 0; kk < 2; ++kk) {
#pragma unroll
        for (int i = 0; i < FH; ++i) a0[i][kk] = rdA(cur, 0, i, kk);
#pragma unroll
        for (int j = 0; j < 4; ++j) bfr[kk][j] = rdB(cur, j, kk);
      }
      if (kt + 1 < NT) stageA(cur ^ 1, 1, kt + 1);
      __builtin_amdgcn_s_setprio(1);
#pragma unroll
      for (int kk = 0; kk < 2; ++kk)
#pragma unroll
        for (int j = 0; j < 4; ++j)
#pragma unroll
          for (int i = 0; i < FH; ++i)
            acc[i][j] = __builtin_amdgcn_mfma_f32_16x16x32_bf16(
                a0[i][kk], bfr[kk][j], acc[i][j], 0, 0, 0);
      __builtin_amdgcn_s_setprio(0);
    }
    __builtin_amdgcn_s_barrier();
    __builtin_amdgcn_sched_barrier(0);
    // ---------------- region 1 (A half 1, reuse bfr) ----------------
    {
      bf16x8 a1[FH][2];
#pragma unroll
      for (int kk = 0; kk < 2; ++kk)
#pragma unroll
        for (int i = 0; i < FH; ++i) a1[i][kk] = rdA(cur, 1, i, kk);
      if (kt + 2 < NT) {
        stageA(cur, 0, kt + 2);
        stageB(cur, 0, kt + 2);
        stageB(cur, 1, kt + 2);
      }
      __builtin_amdgcn_s_setprio(1);
#pragma unroll
      for (int kk = 0; kk < 2; ++kk)
#pragma unroll
        for (int j = 0; j < 4; ++j)
#pragma unroll
          for (int i = 0; i < FH; ++i)
            acc[FH + i][j] = __builtin_amdgcn_mfma_f32_16x16x32_bf16(
                a1[i][kk], bfr[kk][j], acc[FH + i][j], 0, 0, 0);
      __builtin_amdgcn_s_setprio(0);
    }
    if (kt + 2 < NT) {
      if constexpr (KEEP == 6) asm volatile("s_waitcnt vmcnt(6)" ::: "memory");
      else                     asm volatile("s_waitcnt vmcnt(4)" ::: "memory");
      __builtin_amdgcn_sched_barrier(0);
    } else if (kt + 1 < NT) {
      asm volatile("s_waitcnt vmcnt(0)" ::: "memory");
      __builtin_amdgcn_sched_barrier(0);
    }
    __builtin_amdgcn_s_barrier();
    __builtin_amdgcn_sched_barrier(0);
  };

  int kt = 0;
#pragma unroll 1
  for (int it = 0; it < NT / 2; ++it) {
    body(ic<0>{}, kt); ++kt;
    body(ic<1>{}, kt); ++kt;
  }
  if constexpr (NT & 1) body(ic<0>{}, kt);

  // epilogue: C/D layout col=lane&15, row=(lane>>4)*4+reg
  const int rowb = bm * 256 + wmBase + g * 4;
  const int colb = bn * BN + wn + lr;
  if (MODE == 0) {
    const int leaf = bn;   // BN=256 tile == one leaf
#pragma unroll
    for (int q = 0; q < 2; ++q)
#pragma unroll
      for (int i = 0; i < FH; ++i) {
        int rbase = rowb + q * 128 + i * 16;
        float pm[4];
#pragma unroll
        for (int rg = 0; rg < 4; ++rg)
          pm[rg] = probs[(size_t)(rbase + rg) * 16 + leaf];
#pragma unroll
        for (int j = 0; j < 4; ++j) {
          float bias = b1[colb + j * 16];
#pragma unroll
          for (int rg = 0; rg < 4; ++rg) {
            float v = acc[q * FH + i][j][rg] + bias;
            v = v > 0.f ? v : 0.f;
            v *= pm[rg];
            hp[(size_t)(rbase + rg) * K2 + colb + j * 16] = f2bf(v);
          }
        }
      }
  } else {
#pragma unroll
    for (int q = 0; q < 2; ++q)
#pragma unroll
      for (int i = 0; i < FH; ++i) {
        int rbase = rowb + q * 128 + i * 16;
#pragma unroll
        for (int j = 0; j < 4; ++j)
#pragma unroll
          for (int rg = 0; rg < 4; ++rg)
            out[(size_t)(rbase + rg) * N2 + colb + j * 16] = acc[q * FH + i][j][rg];
      }
  }
}

extern "C" void kernel_launch(void* const* d_in, const int* in_sizes, int n_in,
                              void* d_out, int out_size, void* d_ws, size_t ws_size,
                              hipStream_t stream) {
  const float* x      = (const float*)d_in[0];
  const float* node_w = (const float*)d_in[1];
  const float* node_b = (const float*)d_in[2];
  const float* w1     = (const float*)d_in[3];
  const float* b1     = (const float*)d_in[4];
  const float* w2     = (const float*)d_in[5];
  const float* b2     = (const float*)d_in[6];
  float* out = (float*)d_out;

  char* ws = (char*)d_ws;
  ushort_t* xb    = (ushort_t*)(ws);
  ushort_t* w1t   = (ushort_t*)(ws + 16777216);
  ushort_t* w2t   = (ushort_t*)(ws + 25165824);
  ushort_t* hp    = (ushort_t*)(ws + 33685504);
  float*    probs = (float*)   (ws + 101842944);

  k_prep<<<4352, 256, 0, stream>>>(x, node_w, node_b, w1, w2, b2,
                                   xb, probs, w1t, w2t, hp);
  // GEMM1: 8192x4096, K=1024: 32x16=512 blocks, BN=256, LDS 128 KiB
  k_gemm8<16, K1, K1, 256, 0><<<512, 512, 131072, stream>>>(
      xb, w1t, probs, b1, hp, nullptr, N1 / 256);
  // GEMM2: 8192x1024, K=4160: 32x8=256 blocks, BN=128, LDS 96 KiB
  k_gemm8<65, K2, K2, 128, 1><<<256, 512, 98304, stream>>>(
      hp, w2t, nullptr, nullptr, nullptr, out, N2 / 128);
}